// Round 13
// baseline (193.853 us; speedup 1.0000x reference)
//
#include <hip/hip_runtime.h>

// ---------------------------------------------------------------------------
// Geometry: b=64, units=32, d_model=4096, P=16 -> c=2, d=256, C=512,
// dwconv 3x3 s2 16x16->8x8 (hw=64), dk=64; attn 256x256 per (b,cc).
//
// RESTRUCTURING: conv1d (16->32ch) and Linear (over l) commute:
//   out = c1w · (X · W^T) + c1b · rowsum(W) + lin_b
// big GEMM at M=1024; final GEMM is BM=64 x BN=256, wave=64x64 (acc[4][4],
// 2.0 MFMA/ds_read vs 1.33 before -- it was LDS-read-bound), 2 LDS buffers
// (80KB -> 2 blocks/CU), SPLIT-K (2 halves -> 512 blocks fill the device),
// partials summed in the epilogue.
//
// All GEMM-shaped work runs as bf16 hi/lo split MFMA:
//   C = Ah*Bh + Ah*Bl + Al*Bh  (K' = 3K, error ~2^-17 rel).
//
// Workspace (ws = 48 MiB) / d_out (32 MiB) choreography:
//   1) pwkp -> d_out[0..3.1M]
//   2) tTp bf16 [3][4096][1024] @ws 25.2M..50.3M
//   3) qp @ws0, kpp @8.4M, vtp @16.8M  (pipelined pointwise GEMM)
//   4) attn -> Xp @ws 41.9M (over tTp slab 2)
//   5) split_rs: lwp -> d_out (over pwkp); rs @ws0 (over qp)
//   6) gemm_final reads Xp,lwp -> G[2] f32 @ws 8.4M..41.9M
//   7) epilogue reads G0+G1,rs,c1w,c1b,linb -> writes d_out (over lwp)
// ---------------------------------------------------------------------------

typedef short s16x8 __attribute__((ext_vector_type(8)));
typedef float f32x4 __attribute__((ext_vector_type(4)));
typedef const __attribute__((address_space(1))) void* gas_t;
typedef __attribute__((address_space(3))) void* las_t;

__device__ __forceinline__ unsigned short f2bf(float x) {
  unsigned u = __float_as_uint(x);
  unsigned r = u + 0x7fffu + ((u >> 16) & 1u);
  return (unsigned short)(r >> 16);
}
__device__ __forceinline__ float bf2f(unsigned short h) {
  return __uint_as_float((unsigned)h << 16);
}

// ======================= Stage A: patch + dwconv + BN + GELU (batched) =====
__global__ __launch_bounds__(256) void stageA_kernel(
    const float* __restrict__ xq, const float* __restrict__ xk,
    const float* __restrict__ xv, const float* __restrict__ dwk,
    const float* __restrict__ bng, const float* __restrict__ bnb,
    const float* __restrict__ bnm, const float* __restrict__ bnv,
    unsigned short* __restrict__ tTp)
{
  const int i  = blockIdx.y;
  const float* x = (i == 0) ? xq : (i == 1) ? xk : xv;
  const float* dwk_i = dwk + (size_t)i * 4608;
  const int co = i * 512;
  unsigned short* out = tTp + (size_t)i * 4194304;

  const int dd = threadIdx.x;
  const int oh = blockIdx.x & 7;
  const int cc = (blockIdx.x >> 3) & 1;
  const int b  = blockIdx.x >> 4;
  const int ch = cc * 256 + dd;

  float r[3][16];
#pragma unroll
  for (int kh = 0; kh < 3; ++kh) {
    int ih = 2 * oh - 1 + kh;
    if (ih >= 0 && ih <= 15) {
      const float* p = x + (size_t)(b * 32 + cc * 16 + ih) * 4096 + dd * 16;
#pragma unroll
      for (int jq = 0; jq < 4; ++jq)
        *(float4*)&r[kh][jq * 4] = *(const float4*)(p + jq * 4);
    } else {
#pragma unroll
      for (int j = 0; j < 16; ++j) r[kh][j] = 0.f;
    }
  }
  float w9[9];
#pragma unroll
  for (int j = 0; j < 9; ++j) w9[j] = dwk_i[ch * 9 + j];
  const float scale = bng[co + ch] / sqrtf(bnv[co + ch] + 1e-5f);
  const float shift = bnb[co + ch] - bnm[co + ch] * scale;

#pragma unroll
  for (int ow = 0; ow < 8; ++ow) {
    float acc = 0.f;
#pragma unroll
    for (int kh = 0; kh < 3; ++kh)
#pragma unroll
      for (int kw = 0; kw < 3; ++kw) {
        int iw = 2 * ow - 1 + kw;
        if (iw >= 0 && iw <= 15) acc = fmaf(r[kh][iw], w9[kh * 3 + kw], acc);
      }
    float y = acc * scale + shift;
    y = 0.5f * y * (1.f + erff(y * 0.70710678118654752f));
    unsigned short hi = f2bf(y);
    unsigned short lo = f2bf(y - bf2f(hi));
    size_t rowb = (size_t)(b * 64 + oh * 8 + ow) * 1024;
    out[rowb + ch] = hi;
    out[rowb + 512 + ch] = lo;
  }
}

// ======================= fp32 -> bf16 hi|lo split ==========================
__global__ __launch_bounds__(256) void split_kernel(
    const float* __restrict__ src, unsigned short* __restrict__ dst,
    int kshift, int total4)
{
  int i = blockIdx.x * 256 + threadIdx.x;
  if (i >= total4) return;
  size_t i4 = (size_t)i * 4;
  int K = 1 << kshift;
  int r = (int)(i4 >> kshift);
  int c = (int)(i4 & (size_t)(K - 1));
  float4 xv = *(const float4*)(src + i4);
  unsigned short h0 = f2bf(xv.x), h1 = f2bf(xv.y), h2 = f2bf(xv.z), h3 = f2bf(xv.w);
  unsigned short l0 = f2bf(xv.x - bf2f(h0)), l1 = f2bf(xv.y - bf2f(h1));
  unsigned short l2 = f2bf(xv.z - bf2f(h2)), l3 = f2bf(xv.w - bf2f(h3));
  unsigned short* dr = dst + (size_t)r * (K * 2) + c;
  uint2 hp, lp;
  hp.x = (unsigned)h0 | ((unsigned)h1 << 16);
  hp.y = (unsigned)h2 | ((unsigned)h3 << 16);
  lp.x = (unsigned)l0 | ((unsigned)l1 << 16);
  lp.y = (unsigned)l2 | ((unsigned)l3 << 16);
  *(uint2*)dr = hp;
  *(uint2*)(dr + K) = lp;
}

// ======================= split + row-sum (for linw) ========================
__global__ __launch_bounds__(256) void split_rs_kernel(
    const float* __restrict__ src, unsigned short* __restrict__ dst,
    float* __restrict__ rs, int total4)
{
  int i = blockIdx.x * 256 + threadIdx.x;
  if (i >= total4) return;
  size_t i4 = (size_t)i * 4;
  int r = (int)(i4 >> 11);
  int c = (int)(i4 & 2047);
  float4 xv = *(const float4*)(src + i4);
  unsigned short h0 = f2bf(xv.x), h1 = f2bf(xv.y), h2 = f2bf(xv.z), h3 = f2bf(xv.w);
  unsigned short l0 = f2bf(xv.x - bf2f(h0)), l1 = f2bf(xv.y - bf2f(h1));
  unsigned short l2 = f2bf(xv.z - bf2f(h2)), l3 = f2bf(xv.w - bf2f(h3));
  unsigned short* dr = dst + (size_t)r * 4096 + c;
  uint2 hp, lp;
  hp.x = (unsigned)h0 | ((unsigned)h1 << 16);
  hp.y = (unsigned)h2 | ((unsigned)h3 << 16);
  lp.x = (unsigned)l0 | ((unsigned)l1 << 16);
  lp.y = (unsigned)l2 | ((unsigned)l3 << 16);
  *(uint2*)dr = hp;
  *(uint2*)(dr + 2048) = lp;
  float s = xv.x + xv.y + xv.z + xv.w;
#pragma unroll
  for (int off = 1; off < 64; off <<= 1) s += __shfl_xor(s, off, 64);
  if ((threadIdx.x & 63) == 0) atomicAdd(&rs[r], s);
}

// ======================= pointwise: PIPELINED split GEMM (z=3 batched) =====
// BM=64, BN=128, BK=64, 4 waves, 3 LDS buffers, counted vmcnt(6).
// Grid (32,8,3) ONLY.
__global__ __launch_bounds__(256, 2) void gemm_pw_pipe_kernel(
    const unsigned short* __restrict__ Aall, const unsigned short* __restrict__ Ball,
    unsigned short* __restrict__ Call)
{
  __shared__ unsigned short lds[36864];    // 3 x 24576 B
  const int t = threadIdx.x;

  const int flat = (blockIdx.z * 8 + blockIdx.y) * 32 + blockIdx.x;  // 0..767
  const int xcd = flat & 7;
  const int ii = flat >> 3;            // 0..95
  const int n0 = (xcd * 4 + (ii & 3)) * 128;
  const int rem = ii >> 2;             // 0..23
  const int m0 = (rem & 7) * 64;
  const int z = rem >> 3;              // 0..2

  const unsigned short* A = Aall + (size_t)z * 524288;    // [512][1024]
  const unsigned short* B = Ball + (size_t)z * 4194304;   // [4096][1024]
  unsigned short* Cq = Call + (size_t)z * 4194304;

  const int K = 512, twoK = 1024, Km = 511, nt = 24;

  const int lane = t & 63;
  const int wv = t >> 6;
  const int colbase = wv * 32;
  const int h = lane & 15, g = lane >> 4;

  f32x4 acc[4][2];
#pragma unroll
  for (int mf = 0; mf < 4; ++mf)
#pragma unroll
    for (int nf = 0; nf < 2; ++nf)
      acc[mf][nf] = (f32x4){0.f, 0.f, 0.f, 0.f};

  int arow[2], ablk[2], brow[4], bblk[4];
#pragma unroll
  for (int it = 0; it < 2; ++it) {
    int s = it * 256 + t;
    arow[it] = s >> 3;
    ablk[it] = (s & 7) ^ (arow[it] & 7);
  }
#pragma unroll
  for (int it = 0; it < 4; ++it) {
    int s = it * 256 + t;
    brow[it] = s >> 3;
    bblk[it] = (s & 7) ^ (brow[it] & 7);
  }

  auto issueA = [&](int buf, int tt, int it) {
    int kp = tt * 64 + ablk[it] * 8;
    int ac = (kp < twoK) ? (kp & Km) : (kp - K);
    __builtin_amdgcn_global_load_lds(
        (gas_t)(const void*)(A + (size_t)(m0 + arow[it]) * twoK + ac),
        (las_t)(void*)((char*)lds + (buf * 24576 + it * 4096 + t * 16)), 16, 0, 0);
  };
  auto issueB = [&](int buf, int tt, int it) {
    int kp = tt * 64 + bblk[it] * 8;
    int bc = (kp < twoK) ? kp : (kp - twoK);
    __builtin_amdgcn_global_load_lds(
        (gas_t)(const void*)(B + (size_t)(n0 + brow[it]) * twoK + bc),
        (las_t)(void*)((char*)lds + (buf * 24576 + 8192 + it * 4096 + t * 16)), 16, 0, 0);
  };

  int colx[2];
  colx[0] = ((g) ^ (h & 7)) << 4;
  colx[1] = ((4 + g) ^ (h & 7)) << 4;

  auto rdA = [&](int buf, int kk, int mf) -> s16x8 {
    return *(const s16x8*)((const char*)lds +
        (buf * 24576 + (mf * 16 + h) * 128 + colx[kk]));
  };
  auto rdB = [&](int buf, int kk, int nf) -> s16x8 {
    return *(const s16x8*)((const char*)lds +
        (buf * 24576 + 8192 + (colbase + nf * 16 + h) * 128 + colx[kk]));
  };

#define MFMA8(A0, A1, A2, A3, B0, B1) \
  acc[0][0] = __builtin_amdgcn_mfma_f32_16x16x32_bf16(A0, B0, acc[0][0], 0, 0, 0); \
  acc[1][0] = __builtin_amdgcn_mfma_f32_16x16x32_bf16(A1, B0, acc[1][0], 0, 0, 0); \
  acc[2][0] = __builtin_amdgcn_mfma_f32_16x16x32_bf16(A2, B0, acc[2][0], 0, 0, 0); \
  acc[3][0] = __builtin_amdgcn_mfma_f32_16x16x32_bf16(A3, B0, acc[3][0], 0, 0, 0); \
  acc[0][1] = __builtin_amdgcn_mfma_f32_16x16x32_bf16(A0, B1, acc[0][1], 0, 0, 0); \
  acc[1][1] = __builtin_amdgcn_mfma_f32_16x16x32_bf16(A1, B1, acc[1][1], 0, 0, 0); \
  acc[2][1] = __builtin_amdgcn_mfma_f32_16x16x32_bf16(A2, B1, acc[2][1], 0, 0, 0); \
  acc[3][1] = __builtin_amdgcn_mfma_f32_16x16x32_bf16(A3, B1, acc[3][1], 0, 0, 0);

#pragma unroll
  for (int it = 0; it < 2; ++it) issueA(0, 0, it);
#pragma unroll
  for (int it = 0; it < 4; ++it) issueB(0, 0, it);
#pragma unroll
  for (int it = 0; it < 2; ++it) issueA(1, 1, it);
#pragma unroll
  for (int it = 0; it < 4; ++it) issueB(1, 1, it);
  asm volatile("s_waitcnt vmcnt(6)" ::: "memory");
  __builtin_amdgcn_sched_barrier(0);
  __builtin_amdgcn_s_barrier();
  __builtin_amdgcn_sched_barrier(0);

  int bR = 0;
  for (int tt = 0; tt <= nt - 3; ++tt) {
    const int bn2 = (bR >= 1) ? bR - 1 : 2;
    s16x8 a0 = rdA(bR, 0, 0), a1 = rdA(bR, 0, 1), a2 = rdA(bR, 0, 2), a3 = rdA(bR, 0, 3);
    s16x8 b0 = rdB(bR, 0, 0), b1 = rdB(bR, 0, 1);
    issueA(bn2, tt + 2, 0); issueA(bn2, tt + 2, 1); issueB(bn2, tt + 2, 0);
    __builtin_amdgcn_s_barrier();
    __builtin_amdgcn_s_setprio(1);
    MFMA8(a0, a1, a2, a3, b0, b1)
    __builtin_amdgcn_s_setprio(0);
    __builtin_amdgcn_s_barrier();
    a0 = rdA(bR, 1, 0); a1 = rdA(bR, 1, 1); a2 = rdA(bR, 1, 2); a3 = rdA(bR, 1, 3);
    b0 = rdB(bR, 1, 0); b1 = rdB(bR, 1, 1);
    issueB(bn2, tt + 2, 1); issueB(bn2, tt + 2, 2); issueB(bn2, tt + 2, 3);
    __builtin_amdgcn_s_barrier();
    __builtin_amdgcn_s_setprio(1);
    MFMA8(a0, a1, a2, a3, b0, b1)
    __builtin_amdgcn_s_setprio(0);
    asm volatile("s_waitcnt vmcnt(6)" ::: "memory");
    __builtin_amdgcn_sched_barrier(0);
    __builtin_amdgcn_s_barrier();
    __builtin_amdgcn_sched_barrier(0);
    bR = (bR == 2) ? 0 : bR + 1;
  }

  auto compute_tile = [&](int buf) {
#pragma unroll
    for (int kk = 0; kk < 2; ++kk) {
      s16x8 ta0 = rdA(buf, kk, 0), ta1 = rdA(buf, kk, 1);
      s16x8 ta2 = rdA(buf, kk, 2), ta3 = rdA(buf, kk, 3);
      s16x8 tb0 = rdB(buf, kk, 0), tb1 = rdB(buf, kk, 1);
      MFMA8(ta0, ta1, ta2, ta3, tb0, tb1)
    }
  };
  compute_tile(bR);
  __syncthreads();
  compute_tile((bR == 2) ? 0 : bR + 1);
#undef MFMA8

  if (z < 2) {
#pragma unroll
    for (int mf = 0; mf < 4; ++mf) {
      int mbase = m0 + mf * 16 + g * 4;
#pragma unroll
      for (int nf = 0; nf < 2; ++nf) {
        int n = n0 + colbase + nf * 16 + h;
        int bb = n >> 6, d = n & 63;
#pragma unroll
        for (int qq = 0; qq < 4; ++qq) {
          int m = mbase + qq;
          int cc = m >> 8;
          size_t rowb = ((size_t)(bb * 2 + cc) * 256 + (m & 255)) * 128;
          float vvv = acc[mf][nf][qq];
          unsigned short hi = f2bf(vvv);
          unsigned short lo = f2bf(vvv - bf2f(hi));
          Cq[rowb + d] = hi;
          Cq[rowb + 64 + d] = lo;
        }
      }
    }
  } else {
#pragma unroll
    for (int mf = 0; mf < 4; ++mf) {
      int mbase = m0 + mf * 16 + g * 4;
      int cc = mbase >> 8;
      int mc = mbase & 255;
#pragma unroll
      for (int nf = 0; nf < 2; ++nf) {
        int n = n0 + colbase + nf * 16 + h;
        int bb = n >> 6, d = n & 63;
        size_t rowb = ((size_t)(bb * 2 + cc) * 64 + d) * 512;
        ushort4 hv, lv;
        float v0 = acc[mf][nf][0], v1 = acc[mf][nf][1];
        float v2 = acc[mf][nf][2], v3 = acc[mf][nf][3];
        hv.x = f2bf(v0); hv.y = f2bf(v1); hv.z = f2bf(v2); hv.w = f2bf(v3);
        lv.x = f2bf(v0 - bf2f(hv.x)); lv.y = f2bf(v1 - bf2f(hv.y));
        lv.z = f2bf(v2 - bf2f(hv.z)); lv.w = f2bf(v3 - bf2f(hv.w));
        *(ushort4*)&Cq[rowb + mc] = hv;
        *(ushort4*)&Cq[rowb + 256 + mc] = lv;
      }
    }
  }
}

// ======================= final GEMM: G = X' * lwp^T, split-K ===============
// BM=64, BN=256, 4 waves each owning 64x64 (acc[4][4], 2.0 MFMA/ds_read),
// 2 LDS buffers (80 KB -> 2 blocks/CU), counted vmcnt(10), split-K (ks=0/1,
// 48 K-tiles each) -> 512 blocks. Writes partial G[ks]. Grid (32,16) ONLY.
__global__ __launch_bounds__(256) void gemm_final_kernel(
    const unsigned short* __restrict__ A, const unsigned short* __restrict__ B,
    float* __restrict__ C)
{
  __shared__ unsigned short lds[40960];    // 81920 B = 2 x 40960
  const int t = threadIdx.x;

  const int flat = blockIdx.y * 32 + blockIdx.x;   // 0..511
  const int xcd = flat & 7;
  const int ii = flat >> 3;                 // 0..63
  const int n0 = (xcd * 2 + (ii & 1)) * 256;
  const int rem = ii >> 1;                  // 0..31
  const int m0 = (rem & 15) * 64;
  const int ks = rem >> 4;                  // 0..1
  const int base = ks * 48;                 // first K-tile

  const int K = 2048, twoK = 4096, Km = 2047;

  const int lane = t & 63;
  const int wv = t >> 6;
  const int colbase = wv * 64;
  const int h = lane & 15, g = lane >> 4;

  f32x4 acc[4][4];
#pragma unroll
  for (int mf = 0; mf < 4; ++mf)
#pragma unroll
    for (int nf = 0; nf < 4; ++nf)
      acc[mf][nf] = (f32x4){0.f, 0.f, 0.f, 0.f};

  int arow[2], ablk[2], brow[8], bblk[8];
#pragma unroll
  for (int it = 0; it < 2; ++it) {
    int s = it * 256 + t;
    arow[it] = s >> 3;
    ablk[it] = (s & 7) ^ (arow[it] & 7);
  }
#pragma unroll
  for (int it = 0; it < 8; ++it) {
    int s = it * 256 + t;
    brow[it] = s >> 3;                      // 0..255
    bblk[it] = (s & 7) ^ (brow[it] & 7);
  }

  auto issueA = [&](int buf, int tt, int it) {
    int kp = tt * 64 + ablk[it] * 8;
    int ac = (kp < twoK) ? (kp & Km) : (kp - K);
    __builtin_amdgcn_global_load_lds(
        (gas_t)(const void*)(A + (size_t)(m0 + arow[it]) * twoK + ac),
        (las_t)(void*)((char*)lds + (buf * 40960 + it * 4096 + t * 16)), 16, 0, 0);
  };
  auto issueB = [&](int buf, int tt, int it) {
    int kp = tt * 64 + bblk[it] * 8;
    int bc = (kp < twoK) ? kp : (kp - twoK);
    __builtin_amdgcn_global_load_lds(
        (gas_t)(const void*)(B + (size_t)(n0 + brow[it]) * twoK + bc),
        (las_t)(void*)((char*)lds + (buf * 40960 + 8192 + it * 4096 + t * 16)), 16, 0, 0);
  };

  int colx[2];
  colx[0] = ((g) ^ (h & 7)) << 4;
  colx[1] = ((4 + g) ^ (h & 7)) << 4;

  auto rdA = [&](int buf, int kk, int mf) -> s16x8 {
    return *(const s16x8*)((const char*)lds +
        (buf * 40960 + (mf * 16 + h) * 128 + colx[kk]));
  };
  auto rdB = [&](int buf, int kk, int nf) -> s16x8 {
    return *(const s16x8*)((const char*)lds +
        (buf * 40960 + 8192 + (colbase + nf * 16 + h) * 128 + colx[kk]));
  };

#define MFMA16(BQ) \
  { s16x8 a0 = rdA(BQ##buf, BQ##kk, 0), a1 = rdA(BQ##buf, BQ##kk, 1); \
    s16x8 a2 = rdA(BQ##buf, BQ##kk, 2), a3 = rdA(BQ##buf, BQ##kk, 3); \
    s16x8 b0 = rdB(BQ##buf, BQ##kk, 0), b1 = rdB(BQ##buf, BQ##kk, 1); \
    s16x8 b2 = rdB(BQ##buf, BQ##kk, 2), b3 = rdB(BQ##buf, BQ##kk, 3); \
    acc[0][0] = __builtin_amdgcn_mfma_f32_16x16x32_bf16(a0, b0, acc[0][0], 0, 0, 0); \
    acc[1][0] = __builtin_amdgcn_mfma_f32_16x16x32_bf16(a1, b0, acc[1][0], 0, 0, 0); \
    acc[2][0] = __builtin_amdgcn_mfma_f32_16x16x32_bf16(a2, b0, acc[2][0], 0, 0, 0); \
    acc[3][0] = __builtin_amdgcn_mfma_f32_16x16x32_bf16(a3, b0, acc[3][0], 0, 0, 0); \
    acc[0][1] = __builtin_amdgcn_mfma_f32_16x16x32_bf16(a0, b1, acc[0][1], 0, 0, 0); \
    acc[1][1] = __builtin_amdgcn_mfma_f32_16x16x32_bf16(a1, b1, acc[1][1], 0, 0, 0); \
    acc[2][1] = __builtin_amdgcn_mfma_f32_16x16x32_bf16(a2, b1, acc[2][1], 0, 0, 0); \
    acc[3][1] = __builtin_amdgcn_mfma_f32_16x16x32_bf16(a3, b1, acc[3][1], 0, 0, 0); \
    acc[0][2] = __builtin_amdgcn_mfma_f32_16x16x32_bf16(a0, b2, acc[0][2], 0, 0, 0); \
    acc[1][2] = __builtin_amdgcn_mfma_f32_16x16x32_bf16(a1, b2, acc[1][2], 0, 0, 0); \
    acc[2][2] = __builtin_amdgcn_mfma_f32_16x16x32_bf16(a2, b2, acc[2][2], 0, 0, 0); \
    acc[3][2] = __builtin_amdgcn_mfma_f32_16x16x32_bf16(a3, b2, acc[3][2], 0, 0, 0); \
    acc[0][3] = __builtin_amdgcn_mfma_f32_16x16x32_bf16(a0, b3, acc[0][3], 0, 0, 0); \
    acc[1][3] = __builtin_amdgcn_mfma_f32_16x16x32_bf16(a1, b3, acc[1][3], 0, 0, 0); \
    acc[2][3] = __builtin_amdgcn_mfma_f32_16x16x32_bf16(a2, b3, acc[2][3], 0, 0, 0); \
    acc[3][3] = __builtin_amdgcn_mfma_f32_16x16x32_bf16(a3, b3, acc[3][3], 0, 0, 0); }

  // ---- prologue: stage tiles base, base+1 (10 loads each) ----
#pragma unroll
  for (int it = 0; it < 2; ++it) issueA(0, base, it);
#pragma unroll
  for (int it = 0; it < 8; ++it) issueB(0, base, it);
#pragma unroll
  for (int it = 0; it < 2; ++it) issueA(1, base + 1, it);
#pragma unroll
  for (int it = 0; it < 8; ++it) issueB(1, base + 1, it);
  asm volatile("s_waitcnt vmcnt(10)" ::: "memory");
  __builtin_amdgcn_sched_barrier(0);
  __builtin_amdgcn_s_barrier();
  __builtin_amdgcn_sched_barrier(0);

  int bR = 0;
  for (int tt = base; tt <= base + 45; ++tt) {
    // ---- phase 0 (kk=0): 8 ds_read + 16 MFMA ----
    {
      const int p0buf = bR, p0kk = 0;
      __builtin_amdgcn_s_setprio(1);
      MFMA16(p0)
      __builtin_amdgcn_s_setprio(0);
    }
    __builtin_amdgcn_s_barrier();
    // ---- phase 1 (kk=1): 8 ds_read; drain lgkm; barrier; THEN prefetch
    //      tt+2 into THIS buffer (safe: all reads of it are done) ----
    {
      s16x8 a0 = rdA(bR, 1, 0), a1 = rdA(bR, 1, 1), a2 = rdA(bR, 1, 2), a3 = rdA(bR, 1, 3);
      s16x8 b0 = rdB(bR, 1, 0), b1 = rdB(bR, 1, 1), b2 = rdB(bR, 1, 2), b3 = rdB(bR, 1, 3);
      asm volatile("s_waitcnt lgkmcnt(0)" ::: "memory");
      __builtin_amdgcn_sched_barrier(0);
      __builtin_amdgcn_s_barrier();       // all waves' reads of buf bR done
      issueA(bR, tt + 2, 0); issueA(bR, tt + 2, 1);
#pragma unroll
      for (int it = 0; it < 8; ++it) issueB(bR, tt + 2, it);
      __builtin_amdgcn_s_setprio(1);
      acc[0][0] = __builtin_amdgcn_mfma_f32_16x16x32_bf16(a0, b0, acc[0][0], 0, 0, 0);
      acc[1][0] = __builtin_amdgcn_mfma_f32_16x16x32_bf16(a1, b0, acc[1][0], 0, 0, 0);
      acc[2][0] = __builtin_amdgcn_mfma_f32_16x16x32_bf16(a2, b0, acc[2][0], 0, 0, 0);
      acc[3][0] = __builtin_amdgcn_mfma_f32_16x16x32_bf16(a3, b0, acc[3][0], 0, 0, 0);
      acc[0][1] = __builtin_amdgcn_mfma_f32_16x16x32_bf16(a0, b1, acc[0][1], 0, 0, 0);
      acc[1][1] = __builtin_amdgcn_mfma_f32_16x16x32_bf16(a1, b1, acc[1][1], 0, 0, 0);
      acc[2][1] = __builtin_amdgcn_mfma_f32_16x16x32_bf16(a2, b1, acc[2][1], 0, 0, 0);
      acc[3][1] = __builtin_amdgcn_mfma_f32_16x16x32_bf16(a3, b1, acc[3][1], 0, 0, 0);
      acc[0][2] = __builtin_amdgcn_mfma_f32_16x16x32_bf16(a0, b2, acc[0][2], 0, 0, 0);
      acc[1][2] = __builtin_amdgcn_mfma_f32_16x16x32_bf16(a1, b2, acc[1][2], 0, 0, 0);
      acc[2][2] = __builtin_amdgcn_mfma_f32_16x16x32_bf16(a2, b2, acc[2][2], 0, 0, 0);
      acc[3][2] = __builtin_amdgcn_mfma_f32_16x16x32_bf16(a3, b2, acc[3][2], 0, 0, 0);
      acc[0][3] = __builtin_amdgcn_mfma_f32_16x16x32_bf16(a0, b3, acc[0][3], 0, 0, 0);
      acc[1][3] = __builtin_amdgcn_mfma_f32_16x16x32_bf16(a1, b3, acc[1][3], 0, 0, 0);
      acc[2][3] = __builtin_amdgcn_mfma_f32_16x16x32_bf16(a2, b3, acc[2][3], 0, 0, 0);
      acc[3][3] = __builtin_amdgcn_mfma_f32_16x16x32_bf16(a3, b3, acc[3][3], 0, 0, 0);
      __builtin_amdgcn_s_setprio(0);
    }
    asm volatile("s_waitcnt vmcnt(10)" ::: "memory");   // tt+1 landed
    __builtin_amdgcn_sched_barrier(0);
    __builtin_amdgcn_s_barrier();
    __builtin_amdgcn_sched_barrier(0);
    bR ^= 1;
  }

  // ---- tail: tiles base+46 (ready), base+47 (drain) ----
  {
    const int t0buf = bR, t0kk = 0;
    MFMA16(t0)
    const int t1buf = bR, t1kk = 1;
    MFMA16(t1)
  }
  __syncthreads();
  {
    const int t2buf = bR ^ 1, t2kk = 0;
    MFMA16(t2)
    const int t3buf = bR ^ 1, t3kk = 1;
    MFMA16(t3)
  }
#undef MFMA16

  float* Cks = C + (size_t)ks * 4194304;
#pragma unroll
  for (int mf = 0; mf < 4; ++mf) {
    int mbase = m0 + mf * 16 + g * 4;
#pragma unroll
    for (int nf = 0; nf < 4; ++nf) {
      int n = n0 + colbase + nf * 16 + h;
#pragma unroll
      for (int qq = 0; qq < 4; ++qq)
        Cks[(size_t)(mbase + qq) * 4096 + n] = acc[mf][nf][qq];
    }
  }
}

// ======================= Attention (MFMA, split bf16) ======================
__global__ __launch_bounds__(256) void attn_mfma_kernel(
    const unsigned short* __restrict__ qp, const unsigned short* __restrict__ kp,
    const unsigned short* __restrict__ vtp, const float* __restrict__ pos,
    unsigned short* __restrict__ Xp)
{
  __shared__ char smem[59904];
  unsigned short* qs = (unsigned short*)smem;
  unsigned short* kv = (unsigned short*)(smem + 8704);
  float* sc = (float*)(smem + 26112);
  unsigned short* ps = (unsigned short*)(smem + 26112);

  const int t = threadIdx.x;
  const int rt = blockIdx.x, cc = blockIdx.y, b = blockIdx.z;
  const int i0 = rt * 32;
  const size_t qkbase = (size_t)(b * 2 + cc) * 256;
  const size_t vbase  = (size_t)(b * 2 + cc) * 64;

  const int lane = t & 63, wvv = t >> 6;
  const int h = lane & 15, g = lane >> 4;

#pragma unroll
  for (int rep = 0; rep < 2; ++rep) {
    int s = t + rep * 256;
    int row = s >> 4;
    int blk = s & 15;
    int4 val = *(const int4*)(qp + (qkbase + i0 + row) * 128 + blk * 8);
    *(int4*)((char*)qs + row * 272 + blk * 16) = val;
  }

  for (int c = 0; c < 4; ++c) {
    __syncthreads();
#pragma unroll
    for (int p2 = 0; p2 < 4; ++p2) {
      int s = t + p2 * 256;
      int row = s >> 4;
      int blk = s & 15;
      int4 val = *(const int4*)(kp + (qkbase + c * 64 + row) * 128 + blk * 8);
      *(int4*)((char*)kv + row * 272 + blk * 16) = val;
    }
    __syncthreads();
    f32x4 acc2[2];
    acc2[0] = (f32x4){0.f, 0.f, 0.f, 0.f};
    acc2[1] = (f32x4){0.f, 0.f, 0.f, 0.f};
#pragma unroll
    for (int kk = 0; kk < 6; ++kk) {
      int abase = (kk < 2) ? kk * 32 : (kk < 4) ? 64 + (kk - 2) * 32 : (kk - 4) * 32;
      int bbase = (kk < 2) ? kk * 32 : (kk < 4) ? (kk - 2) * 32 : 64 + (kk - 4) * 32;
      s16x8 bfrag = *(const s16x8*)((char*)kv + (wvv * 16 + h) * 272 + (bbase + g * 8) * 2);
#pragma unroll
      for (int mf = 0; mf < 2; ++mf) {
        s16x8 afrag = *(const s16x8*)((char*)qs + (mf * 16 + h) * 272 + (abase + g * 8) * 2);
        acc2[mf] = __builtin_amdgcn_mfma_f32_16x16x32_bf16(afrag, bfrag, acc2[mf], 0, 0, 0);
      }
    }
#pragma unroll
    for (int mf = 0; mf < 2; ++mf)
#pragma unroll
      for (int qq = 0; qq < 4; ++qq) {
        int row = mf * 16 + g * 4 + qq;
        int j = c * 64 + wvv * 16 + h;
        sc[row * 264 + j] = acc2[mf][qq] * 0.125f +
            pos[((size_t)cc * 256 + i0 + row) * 256 + j];
      }
  }
  __syncthreads();

  {
    const int r = t >> 3, j8 = t & 7;
    float e[32];
    float mx = -3.4e38f;
#pragma unroll
    for (int jj = 0; jj < 32; ++jj) {
      e[jj] = sc[r * 264 + j8 + 8 * jj];
      mx = fmaxf(mx, e[jj]);
    }
#pragma unroll
    for (int mset = 1; mset < 8; mset <<= 1) mx = fmaxf(mx, __shfl_xor(mx, mset, 64));
    float sum = 0.f;
#pragma unroll
    for (int jj = 0; jj < 32; ++jj) {
      e[jj] = expf(e[jj] - mx);
      sum += e[jj];
    }
#pragma unroll
    for (int mset = 1; mset < 8; mset <<= 1) sum += __shfl_xor(sum, mset, 64);
    float inv = 1.f / sum;
    __syncthreads();
#pragma unroll
    for (int jj = 0; jj < 32; ++jj) {
      float pv = e[jj] * inv;
      unsigned short hi = f2bf(pv);
      unsigned short lo = f2bf(pv - bf2f(hi));
      int j = j8 + 8 * jj;
      ps[r * 528 + j] = hi;
      ps[r * 528 + 264 + j] = lo;
    }
  }

  f32x4 oacc[2];
  oacc[0] = (f32x4){0.f, 0.f, 0.f, 0.f};
  oacc[1] = (f32x4){0.f, 0.f, 0.f, 0.f};
  for (int c = 0; c < 4; ++c) {
    __syncthreads();
#pragma unroll
    for (int p2 = 0; p2 < 4; ++p2) {
      int s = t + p2 * 256, row = s >> 4, blk = s & 15;
      int col = (blk < 8) ? (c * 64 + blk * 8) : (256 + c * 64 + (blk - 8) * 8);
      int4 val = *(const int4*)(vtp + (vbase + row) * 512 + col);
      *(int4*)((char*)kv + row * 272 + blk * 16) = val;
    }
    __syncthreads();
#pragma unroll
    for (int kk = 0; kk < 6; ++kk) {
      int abase = (kk < 2) ? (c * 64 + kk * 32)
                : (kk < 4) ? (264 + c * 64 + (kk - 2) * 32)
                           : (c * 64 + (kk - 4) * 32);
      int bbase = (kk < 2) ? kk * 32 : (kk < 4) ? (kk - 2) * 32 : 64 + (kk - 4) * 32;
      s16x8 bfrag = *(const s16x8*)((char*)kv + (wvv * 16 + h) * 272 + (bbase + g * 8) * 2);
#pragma unroll
      for (int mf = 0; mf < 2; ++mf) {
        s16x8 afrag = *(const s16x8*)((char*)ps + (mf * 16 + h) * 1056 + (abase + g * 8) * 2);
        oacc[mf] = __builtin_amdgcn_mfma_f32_16x16x32_bf16(afrag, bfrag, oacc[mf], 0, 0, 0);
      }
    }
  }
  {
    int Xrow = b * 16 + cc * 8 + wvv * 2 + (h >> 3);
    int c7 = h & 7;
#pragma unroll
    for (int mf = 0; mf < 2; ++mf)
#pragma unroll
      for (int qq = 0; qq < 4; ++qq) {
        int dd = i0 + mf * 16 + g * 4 + qq;
        float vvv = oacc[mf][qq];
        unsigned short hi = f2bf(vvv);
        unsigned short lo = f2bf(vvv - bf2f(hi));
        size_t base = (size_t)Xrow * 4096 + dd * 8 + c7;
        Xp[base] = hi;
        Xp[base + 2048] = lo;
      }
  }
}

// ======================= epilogue: out = c1w*(G0+G1) + c1b*rs + lin_b =====
__global__ __launch_bounds__(256) void epilogue_kernel(
    const float* __restrict__ G, const float* __restrict__ rs,
    const float* __restrict__ c1w, const float* __restrict__ c1b,
    const float* __restrict__ linb, float* __restrict__ out)
{
  __shared__ float W[512];
  __shared__ float Bp[32];
  const int t = threadIdx.x;
  const int ntile = blockIdx.x;   // 0..15
  const int b = blockIdx.y;       // 0..63
  W[t] = c1w[t];
  W[t + 256] = c1w[t + 256];
  if (t < 32) Bp[t] = c1b[t];
  __syncthreads();
  const int n = ntile * 256 + t;
  float gv[16];
#pragma unroll
  for (int ch = 0; ch < 16; ++ch) {
    size_t off = (size_t)(b * 16 + ch) * 4096 + n;
    gv[ch] = G[off] + G[4194304 + off];
  }
  const float rsn = rs[n];
  const float lbn = linb[n];
#pragma unroll
  for (int o = 0; o < 32; ++o) {
    float s = lbn + Bp[o] * rsn;
#pragma unroll
    for (int ch = 0; ch < 16; ++ch) s = fmaf(W[o * 16 + ch], gv[ch], s);
    out[(size_t)(b * 32 + o) * 4096 + n] = s;
  }
}

// ======================= launch ============================================
extern "C" void kernel_launch(void* const* d_in, const int* in_sizes, int n_in,
                              void* d_out, int out_size, void* d_ws, size_t ws_size,
                              hipStream_t stream) {
  const float* q    = (const float*)d_in[0];
  const float* k    = (const float*)d_in[1];
  const float* v    = (const float*)d_in[2];
  const float* dwk  = (const float*)d_in[3];
  const float* bng  = (const float*)d_in[4];
  const float* bnb  = (const float*)d_in[5];
  const float* bnm  = (const float*)d_in[6];
  const float* bnv  = (const float*)d_in[7];
  const float* pwk  = (const float*)d_in[8];
  const float* pos  = (const float*)d_in[9];
  const float* c1w  = (const float*)d_in[10];
  const float* c1b  = (const float*)d_in[11];
  const float* linw = (const float*)d_in[12];
  const float* linb = (const float*)d_in[13];
  float* out = (float*)d_out;

  if (ws_size < 50331648u) return;

  char* ws = (char*)d_ws;
  unsigned short* qp   = (unsigned short*)(ws + 0);          //  8,388,608
  unsigned short* kpp  = (unsigned short*)(ws + 8388608);    //  8,388,608
  unsigned short* vtp  = (unsigned short*)(ws + 16777216);   //  8,388,608
  unsigned short* tTp  = (unsigned short*)(ws + 25165824);   // 25,165,824
  unsigned short* pwkp = (unsigned short*)d_out;             //  3,145,728 (d_out scratch)
  unsigned short* Xp   = (unsigned short*)(ws + 41943040);   //  8,388,608 (over tTp slab 2)
  float*          rs   = (float*)(ws + 0);                   //     16,384 (over qp)
  unsigned short* lwp  = (unsigned short*)d_out;             // 33,554,432 (d_out scratch)
  float*          G    = (float*)(ws + 8388608);             // 33,554,432 (G[2], over kpp/vtp/tTp01)

  // 1) split pointwise weights (into d_out scratch)
  split_kernel<<<768, 256, 0, stream>>>(pwk, pwkp, 9, 196608);

  // 2) dwconv+BN+GELU, all three inputs -> tTp
  stageA_kernel<<<dim3(1024, 3), 256, 0, stream>>>(
      q, k, v, dwk, bng, bnb, bnm, bnv, tTp);

  // 3) pointwise GEMMs (pipelined) -> qp/kpp/vtp
  gemm_pw_pipe_kernel<<<dim3(32, 8, 3), 256, 0, stream>>>(pwkp, tTp, qp);

  // 4) attention -> X' split-bf16 @ws 41.9M (over tTp slab 2)
  attn_mfma_kernel<<<dim3(8, 2, 64), 256, 0, stream>>>(qp, kpp, vtp, pos, Xp);

  // 5) split linw (+ row sums) into d_out scratch / ws
  hipMemsetAsync(rs, 0, 16384, stream);
  split_rs_kernel<<<8192, 256, 0, stream>>>(linw, lwp, rs, 2097152);

  // 6) G[ks] = X' * lwp^T partials  (split-K, 512 blocks)
  gemm_final_kernel<<<dim3(32, 16), 256, 0, stream>>>(Xp, lwp, G);

  // 7) out = c1w*(G0+G1) + c1b*rs + lin_b
  epilogue_kernel<<<dim3(16, 64), 256, 0, stream>>>(G, rs, c1w, c1b, linb, out);
}

// Round 14
// 182.594 us; speedup vs baseline: 1.0617x; 1.0617x over previous
//
#include <hip/hip_runtime.h>

// ---------------------------------------------------------------------------
// Geometry: b=64, units=32, d_model=4096, P=16 -> c=2, d=256, C=512,
// dwconv 3x3 s2 16x16->8x8 (hw=64), dk=64; attn 256x256 per (b,cc).
//
// RESTRUCTURING: conv1d (16->32ch) and Linear (over l) commute:
//   out = c1w · (X · W^T) + c1b · rowsum(W) + lin_b
// big GEMM at M=1024. Final GEMM = R4's BM=256xBN=128 8-wave 4-phase
// 3-LDS-buffer pipe (measured 930 TF-split) + SPLIT-K x2 so the grid is
// 4m x 32n x 2ks = 256 blocks (1 block/CU, full device). Partials G[2]
// summed in the epilogue.
//
// All GEMM-shaped work runs as bf16 hi/lo split MFMA:
//   C = Ah*Bh + Ah*Bl + Al*Bh  (K' = 3K, error ~2^-17 rel).
//
// Workspace (ws = 48 MiB) / d_out (32 MiB) choreography:
//   1) pwkp -> d_out[0..3.1M]
//   2) tTp bf16 [3][4096][1024] @ws 25.2M..50.3M
//   3) qp @ws0, kpp @8.4M, vtp @16.8M  (naive batched pointwise GEMM)
//   4) attn -> Xp @ws 41.9M (over tTp slab 2)
//   5) split_rs: lwp -> d_out (over pwkp); rs @ws0 (over qp)
//   6) gemm_final reads Xp,lwp -> G[2] f32 @ws 8.4M..41.9M
//   7) epilogue reads G0+G1,rs,c1w,c1b,linb -> writes d_out (over lwp)
// ---------------------------------------------------------------------------

typedef short s16x8 __attribute__((ext_vector_type(8)));
typedef float f32x4 __attribute__((ext_vector_type(4)));
typedef const __attribute__((address_space(1))) void* gas_t;
typedef __attribute__((address_space(3))) void* las_t;

__device__ __forceinline__ unsigned short f2bf(float x) {
  unsigned u = __float_as_uint(x);
  unsigned r = u + 0x7fffu + ((u >> 16) & 1u);
  return (unsigned short)(r >> 16);
}
__device__ __forceinline__ float bf2f(unsigned short h) {
  return __uint_as_float((unsigned)h << 16);
}

// ======================= Stage A: patch + dwconv + BN + GELU (batched) =====
__global__ __launch_bounds__(256) void stageA_kernel(
    const float* __restrict__ xq, const float* __restrict__ xk,
    const float* __restrict__ xv, const float* __restrict__ dwk,
    const float* __restrict__ bng, const float* __restrict__ bnb,
    const float* __restrict__ bnm, const float* __restrict__ bnv,
    unsigned short* __restrict__ tTp)
{
  const int i  = blockIdx.y;
  const float* x = (i == 0) ? xq : (i == 1) ? xk : xv;
  const float* dwk_i = dwk + (size_t)i * 4608;
  const int co = i * 512;
  unsigned short* out = tTp + (size_t)i * 4194304;

  const int dd = threadIdx.x;
  const int oh = blockIdx.x & 7;
  const int cc = (blockIdx.x >> 3) & 1;
  const int b  = blockIdx.x >> 4;
  const int ch = cc * 256 + dd;

  float r[3][16];
#pragma unroll
  for (int kh = 0; kh < 3; ++kh) {
    int ih = 2 * oh - 1 + kh;
    if (ih >= 0 && ih <= 15) {
      const float* p = x + (size_t)(b * 32 + cc * 16 + ih) * 4096 + dd * 16;
#pragma unroll
      for (int jq = 0; jq < 4; ++jq)
        *(float4*)&r[kh][jq * 4] = *(const float4*)(p + jq * 4);
    } else {
#pragma unroll
      for (int j = 0; j < 16; ++j) r[kh][j] = 0.f;
    }
  }
  float w9[9];
#pragma unroll
  for (int j = 0; j < 9; ++j) w9[j] = dwk_i[ch * 9 + j];
  const float scale = bng[co + ch] / sqrtf(bnv[co + ch] + 1e-5f);
  const float shift = bnb[co + ch] - bnm[co + ch] * scale;

#pragma unroll
  for (int ow = 0; ow < 8; ++ow) {
    float acc = 0.f;
#pragma unroll
    for (int kh = 0; kh < 3; ++kh)
#pragma unroll
      for (int kw = 0; kw < 3; ++kw) {
        int iw = 2 * ow - 1 + kw;
        if (iw >= 0 && iw <= 15) acc = fmaf(r[kh][iw], w9[kh * 3 + kw], acc);
      }
    float y = acc * scale + shift;
    y = 0.5f * y * (1.f + erff(y * 0.70710678118654752f));
    unsigned short hi = f2bf(y);
    unsigned short lo = f2bf(y - bf2f(hi));
    size_t rowb = (size_t)(b * 64 + oh * 8 + ow) * 1024;
    out[rowb + ch] = hi;
    out[rowb + 512 + ch] = lo;
  }
}

// ======================= fp32 -> bf16 hi|lo split ==========================
__global__ __launch_bounds__(256) void split_kernel(
    const float* __restrict__ src, unsigned short* __restrict__ dst,
    int kshift, int total4)
{
  int i = blockIdx.x * 256 + threadIdx.x;
  if (i >= total4) return;
  size_t i4 = (size_t)i * 4;
  int K = 1 << kshift;
  int r = (int)(i4 >> kshift);
  int c = (int)(i4 & (size_t)(K - 1));
  float4 xv = *(const float4*)(src + i4);
  unsigned short h0 = f2bf(xv.x), h1 = f2bf(xv.y), h2 = f2bf(xv.z), h3 = f2bf(xv.w);
  unsigned short l0 = f2bf(xv.x - bf2f(h0)), l1 = f2bf(xv.y - bf2f(h1));
  unsigned short l2 = f2bf(xv.z - bf2f(h2)), l3 = f2bf(xv.w - bf2f(h3));
  unsigned short* dr = dst + (size_t)r * (K * 2) + c;
  uint2 hp, lp;
  hp.x = (unsigned)h0 | ((unsigned)h1 << 16);
  hp.y = (unsigned)h2 | ((unsigned)h3 << 16);
  lp.x = (unsigned)l0 | ((unsigned)l1 << 16);
  lp.y = (unsigned)l2 | ((unsigned)l3 << 16);
  *(uint2*)dr = hp;
  *(uint2*)(dr + K) = lp;
}

// ======================= split + row-sum (for linw) ========================
__global__ __launch_bounds__(256) void split_rs_kernel(
    const float* __restrict__ src, unsigned short* __restrict__ dst,
    float* __restrict__ rs, int total4)
{
  int i = blockIdx.x * 256 + threadIdx.x;
  if (i >= total4) return;
  size_t i4 = (size_t)i * 4;
  int r = (int)(i4 >> 11);
  int c = (int)(i4 & 2047);
  float4 xv = *(const float4*)(src + i4);
  unsigned short h0 = f2bf(xv.x), h1 = f2bf(xv.y), h2 = f2bf(xv.z), h3 = f2bf(xv.w);
  unsigned short l0 = f2bf(xv.x - bf2f(h0)), l1 = f2bf(xv.y - bf2f(h1));
  unsigned short l2 = f2bf(xv.z - bf2f(h2)), l3 = f2bf(xv.w - bf2f(h3));
  unsigned short* dr = dst + (size_t)r * 4096 + c;
  uint2 hp, lp;
  hp.x = (unsigned)h0 | ((unsigned)h1 << 16);
  hp.y = (unsigned)h2 | ((unsigned)h3 << 16);
  lp.x = (unsigned)l0 | ((unsigned)l1 << 16);
  lp.y = (unsigned)l2 | ((unsigned)l3 << 16);
  *(uint2*)dr = hp;
  *(uint2*)(dr + 2048) = lp;
  float s = xv.x + xv.y + xv.z + xv.w;
#pragma unroll
  for (int off = 1; off < 64; off <<= 1) s += __shfl_xor(s, off, 64);
  if ((threadIdx.x & 63) == 0) atomicAdd(&rs[r], s);
}

// ======================= pointwise: bf16-split MFMA NT GEMM (batched z=3) ==
// BM=64 x 128 tile, 4 waves 1x4, naive 2-barrier (R10 known-good).
__global__ __launch_bounds__(256) void gemm_split_kernel(
    const unsigned short* __restrict__ Aall, const unsigned short* __restrict__ Ball,
    unsigned short* __restrict__ Call, int M, int N, int K)
{
  __shared__ unsigned short sA[4096];    // [64][64]
  __shared__ unsigned short sB[8192];    // [128][64]
  const int t = threadIdx.x;
  const int z = blockIdx.z;
  const unsigned short* A = Aall + (size_t)z * 524288;
  const unsigned short* B = Ball + (size_t)z * 4194304;
  unsigned short* Cq = Call + (size_t)z * 4194304;
  const int m0 = blockIdx.y * 64, n0 = blockIdx.x * 128;
  const int Kp = 3 * K, twoK = 2 * K, Km = K - 1;
  const int lane = t & 63;
  const int wv = t >> 6;
  const int colbase = wv * 32;
  const int h = lane & 15, g = lane >> 4;

  f32x4 acc[4][2];
#pragma unroll
  for (int mf = 0; mf < 4; ++mf)
#pragma unroll
    for (int nf = 0; nf < 2; ++nf)
      acc[mf][nf] = (f32x4){0.f, 0.f, 0.f, 0.f};

  int srow[4], sblk[4];
#pragma unroll
  for (int it = 0; it < 4; ++it) {
    int s = it * 256 + t;
    srow[it] = s >> 3;
    sblk[it] = (s & 7) ^ (srow[it] & 7);
  }
  const int ldsw = (t & 192) << 4;

  for (int k0 = 0; k0 < Kp; k0 += 64) {
    __syncthreads();
#pragma unroll
    for (int it = 0; it < 2; ++it) {
      int kp = k0 + sblk[it] * 8;
      int ac = (kp < twoK) ? (kp & Km) : (kp - K);
      const unsigned short* ga = A + (size_t)(m0 + srow[it]) * twoK + ac;
      __builtin_amdgcn_global_load_lds((gas_t)(const void*)ga,
          (las_t)(void*)((char*)sA + (it * 4096 + ldsw)), 16, 0, 0);
    }
#pragma unroll
    for (int it = 0; it < 4; ++it) {
      int kp = k0 + sblk[it] * 8;
      int bc = (kp < twoK) ? kp : (kp - twoK);
      const unsigned short* gb = B + (size_t)(n0 + srow[it]) * twoK + bc;
      __builtin_amdgcn_global_load_lds((gas_t)(const void*)gb,
          (las_t)(void*)((char*)sB + (it * 4096 + ldsw)), 16, 0, 0);
    }
    __syncthreads();

#pragma unroll
    for (int kk = 0; kk < 2; ++kk) {
      s16x8 af[4], bfr[2];
#pragma unroll
      for (int mf = 0; mf < 4; ++mf) {
        int arow = mf * 16 + h;
        int aoff = arow * 128 + (((kk * 4 + g) ^ (h & 7)) << 4);
        af[mf] = *(const s16x8*)((const char*)sA + aoff);
      }
#pragma unroll
      for (int nf = 0; nf < 2; ++nf) {
        int brow = colbase + nf * 16 + h;
        int boff = brow * 128 + (((kk * 4 + g) ^ (h & 7)) << 4);
        bfr[nf] = *(const s16x8*)((const char*)sB + boff);
      }
#pragma unroll
      for (int mf = 0; mf < 4; ++mf)
#pragma unroll
        for (int nf = 0; nf < 2; ++nf)
          acc[mf][nf] = __builtin_amdgcn_mfma_f32_16x16x32_bf16(
              af[mf], bfr[nf], acc[mf][nf], 0, 0, 0);
    }
  }

  if (z < 2) {
    // Q'/K' layout: rows = attention row index (ch%256), cols = d hi|lo
#pragma unroll
    for (int mf = 0; mf < 4; ++mf) {
      int mbase = m0 + mf * 16 + g * 4;
#pragma unroll
      for (int nf = 0; nf < 2; ++nf) {
        int n = n0 + colbase + nf * 16 + h;
        int bb = n >> 6, d = n & 63;
#pragma unroll
        for (int qq = 0; qq < 4; ++qq) {
          int m = mbase + qq;
          int cc = m >> 8;
          size_t rowb = ((size_t)(bb * 2 + cc) * 256 + (m & 255)) * 128;
          float vvv = acc[mf][nf][qq];
          unsigned short hi = f2bf(vvv);
          unsigned short lo = f2bf(vvv - bf2f(hi));
          Cq[rowb + d] = hi;
          Cq[rowb + 64 + d] = lo;
        }
      }
    }
  } else {
    // V^T layout: rows = d, cols = j hi|lo
#pragma unroll
    for (int mf = 0; mf < 4; ++mf) {
      int mbase = m0 + mf * 16 + g * 4;
      int cc = mbase >> 8;
      int mc = mbase & 255;
#pragma unroll
      for (int nf = 0; nf < 2; ++nf) {
        int n = n0 + colbase + nf * 16 + h;
        int bb = n >> 6, d = n & 63;
        size_t rowb = ((size_t)(bb * 2 + cc) * 64 + d) * 512;
        ushort4 hv, lv;
        float v0 = acc[mf][nf][0], v1 = acc[mf][nf][1];
        float v2 = acc[mf][nf][2], v3 = acc[mf][nf][3];
        hv.x = f2bf(v0); hv.y = f2bf(v1); hv.z = f2bf(v2); hv.w = f2bf(v3);
        lv.x = f2bf(v0 - bf2f(hv.x)); lv.y = f2bf(v1 - bf2f(hv.y));
        lv.z = f2bf(v2 - bf2f(hv.z)); lv.w = f2bf(v3 - bf2f(hv.w));
        *(ushort4*)&Cq[rowb + mc] = hv;
        *(ushort4*)&Cq[rowb + 256 + mc] = lv;
      }
    }
  }
}

// ======================= final GEMM: deep pipe + split-K ===================
// G[ks] = X'(1024x4096) * lwp^T over K'-half. BM=256, BN=128, BK=64,
// 8 waves (wm=wv&3, wn=wv>>2), 4x4 16x16 frags/wave, 3 LDS buffers (147KB),
// 4 phases/K-tile, counted vmcnt(6). Grid (32,8) ONLY (hardcoded swizzle:
// each XCD owns 4 n-tiles x 4 m-tiles x 2 ks = 32 blocks; B panel 4MB = L2).
__global__ __launch_bounds__(512, 2) void gemm_final_kernel(
    const unsigned short* __restrict__ A, const unsigned short* __restrict__ B,
    float* __restrict__ C)
{
  __shared__ unsigned short lds[73728];    // 147456 B = 3 x 49152
  const int t = threadIdx.x;

  const int flat = blockIdx.y * 32 + blockIdx.x;  // 0..255
  const int xcd = flat & 7;
  const int ii = flat >> 3;                 // 0..31
  const int n0 = (xcd * 4 + (ii & 3)) * 128;
  const int rem = ii >> 2;                  // 0..7
  const int m0 = (rem & 3) * 256;
  const int ks = rem >> 2;                  // 0..1
  const int base = ks * 48;                 // first K-tile of this half

  const int K = 2048, twoK = 4096, Km = 2047;

  const int lane = t & 63;
  const int wv = t >> 6;
  const int wm = wv & 3, wn = wv >> 2;
  const int h = lane & 15, g = lane >> 4;

  f32x4 acc[4][4];
#pragma unroll
  for (int mf = 0; mf < 4; ++mf)
#pragma unroll
    for (int nf = 0; nf < 4; ++nf)
      acc[mf][nf] = (f32x4){0.f, 0.f, 0.f, 0.f};

  int arow[4], ablk[4], brow[2], bblk[2];
#pragma unroll
  for (int it = 0; it < 4; ++it) {
    int s = it * 512 + t;
    arow[it] = s >> 3;
    ablk[it] = (t & 7) ^ (arow[it] & 7);
  }
#pragma unroll
  for (int it = 0; it < 2; ++it) {
    int s = it * 512 + t;
    brow[it] = s >> 3;
    bblk[it] = (t & 7) ^ (brow[it] & 7);
  }

  auto issueA = [&](int buf, int tt, int it) {
    int kp = tt * 64 + ablk[it] * 8;
    int ac = (kp < twoK) ? (kp & Km) : (kp - K);
    __builtin_amdgcn_global_load_lds(
        (gas_t)(const void*)(A + (size_t)(m0 + arow[it]) * twoK + ac),
        (las_t)(void*)((char*)lds + (buf * 49152 + it * 8192 + t * 16)), 16, 0, 0);
  };
  auto issueB = [&](int buf, int tt, int it) {
    int kp = tt * 64 + bblk[it] * 8;
    int bc = (kp < twoK) ? kp : (kp - twoK);
    __builtin_amdgcn_global_load_lds(
        (gas_t)(const void*)(B + (size_t)(n0 + brow[it]) * twoK + bc),
        (las_t)(void*)((char*)lds + (buf * 49152 + 32768 + it * 8192 + t * 16)), 16, 0, 0);
  };

  const int aoffb = (wm * 64 + h) * 128;
  const int boffb = 32768 + (wn * 64 + h) * 128;
  int colx[2];
  colx[0] = ((g) ^ (h & 7)) << 4;
  colx[1] = ((4 + g) ^ (h & 7)) << 4;

  auto rdA = [&](int buf, int kk, int mf) -> s16x8 {
    return *(const s16x8*)((const char*)lds + (buf * 49152 + aoffb + mf * 2048 + colx[kk]));
  };
  auto rdB = [&](int buf, int kk, int nf) -> s16x8 {
    return *(const s16x8*)((const char*)lds + (buf * 49152 + boffb + nf * 2048 + colx[kk]));
  };

#define MFMA_ROW2(A0, A1, A2, A3, BB, NF) \
  acc[0][NF] = __builtin_amdgcn_mfma_f32_16x16x32_bf16(A0, BB, acc[0][NF], 0, 0, 0); \
  acc[1][NF] = __builtin_amdgcn_mfma_f32_16x16x32_bf16(A1, BB, acc[1][NF], 0, 0, 0); \
  acc[2][NF] = __builtin_amdgcn_mfma_f32_16x16x32_bf16(A2, BB, acc[2][NF], 0, 0, 0); \
  acc[3][NF] = __builtin_amdgcn_mfma_f32_16x16x32_bf16(A3, BB, acc[3][NF], 0, 0, 0);

  // ---- prologue: stage tiles base and base+1 ----
#pragma unroll
  for (int it = 0; it < 4; ++it) issueA(0, base, it);
#pragma unroll
  for (int it = 0; it < 2; ++it) issueB(0, base, it);
#pragma unroll
  for (int it = 0; it < 4; ++it) issueA(1, base + 1, it);
#pragma unroll
  for (int it = 0; it < 2; ++it) issueB(1, base + 1, it);
  asm volatile("s_waitcnt vmcnt(6)" ::: "memory");
  __builtin_amdgcn_sched_barrier(0);
  __builtin_amdgcn_s_barrier();
  __builtin_amdgcn_sched_barrier(0);

  int bR = 0;
  for (int tt = base; tt <= base + 45; ++tt) {
    const int bn2 = (bR >= 1) ? bR - 1 : 2;      // (bR+2)%3
    // ---- phase 0: kk=0 A-frags, B 0..1; prefetch A slices 0,1 ----
    s16x8 a0 = rdA(bR, 0, 0), a1 = rdA(bR, 0, 1), a2 = rdA(bR, 0, 2), a3 = rdA(bR, 0, 3);
    s16x8 b0 = rdB(bR, 0, 0), b1 = rdB(bR, 0, 1);
    issueA(bn2, tt + 2, 0); issueA(bn2, tt + 2, 1);
    __builtin_amdgcn_s_barrier();
    __builtin_amdgcn_s_setprio(1);
    MFMA_ROW2(a0, a1, a2, a3, b0, 0)
    MFMA_ROW2(a0, a1, a2, a3, b1, 1)
    __builtin_amdgcn_s_setprio(0);
    __builtin_amdgcn_s_barrier();
    // ---- phase 1: B 2..3; prefetch A slices 2,3 ----
    s16x8 b2 = rdB(bR, 0, 2), b3 = rdB(bR, 0, 3);
    issueA(bn2, tt + 2, 2); issueA(bn2, tt + 2, 3);
    __builtin_amdgcn_s_barrier();
    __builtin_amdgcn_s_setprio(1);
    MFMA_ROW2(a0, a1, a2, a3, b2, 2)
    MFMA_ROW2(a0, a1, a2, a3, b3, 3)
    __builtin_amdgcn_s_setprio(0);
    __builtin_amdgcn_s_barrier();
    // ---- phase 2: kk=1 A-frags + B 0..1; prefetch B slice 0 ----
    a0 = rdA(bR, 1, 0); a1 = rdA(bR, 1, 1); a2 = rdA(bR, 1, 2); a3 = rdA(bR, 1, 3);
    b0 = rdB(bR, 1, 0); b1 = rdB(bR, 1, 1);
    issueB(bn2, tt + 2, 0);
    __builtin_amdgcn_s_barrier();
    __builtin_amdgcn_s_setprio(1);
    MFMA_ROW2(a0, a1, a2, a3, b0, 0)
    MFMA_ROW2(a0, a1, a2, a3, b1, 1)
    __builtin_amdgcn_s_setprio(0);
    __builtin_amdgcn_s_barrier();
    // ---- phase 3: B 2..3; prefetch B slice 1; counted vmcnt; publish ----
    b2 = rdB(bR, 1, 2); b3 = rdB(bR, 1, 3);
    issueB(bn2, tt + 2, 1);
    __builtin_amdgcn_s_barrier();
    __builtin_amdgcn_s_setprio(1);
    MFMA_ROW2(a0, a1, a2, a3, b2, 2)
    MFMA_ROW2(a0, a1, a2, a3, b3, 3)
    __builtin_amdgcn_s_setprio(0);
    asm volatile("s_waitcnt vmcnt(6)" ::: "memory");
    __builtin_amdgcn_sched_barrier(0);
    __builtin_amdgcn_s_barrier();
    __builtin_amdgcn_sched_barrier(0);
    bR = (bR == 2) ? 0 : bR + 1;
  }

  // ---- tail: tiles base+46 (published) and base+47 (drain) ----
  auto compute_tile = [&](int buf) {
#pragma unroll
    for (int kk = 0; kk < 2; ++kk) {
      s16x8 ta0 = rdA(buf, kk, 0), ta1 = rdA(buf, kk, 1);
      s16x8 ta2 = rdA(buf, kk, 2), ta3 = rdA(buf, kk, 3);
      s16x8 tb0 = rdB(buf, kk, 0), tb1 = rdB(buf, kk, 1);
      s16x8 tb2 = rdB(buf, kk, 2), tb3 = rdB(buf, kk, 3);
      MFMA_ROW2(ta0, ta1, ta2, ta3, tb0, 0)
      MFMA_ROW2(ta0, ta1, ta2, ta3, tb1, 1)
      MFMA_ROW2(ta0, ta1, ta2, ta3, tb2, 2)
      MFMA_ROW2(ta0, ta1, ta2, ta3, tb3, 3)
    }
  };
  compute_tile(bR);
  __syncthreads();
  compute_tile((bR == 2) ? 0 : bR + 1);
#undef MFMA_ROW2

  float* Cks = C + (size_t)ks * 4194304;
#pragma unroll
  for (int mf = 0; mf < 4; ++mf) {
    int mbase = m0 + wm * 64 + mf * 16 + g * 4;
#pragma unroll
    for (int nf = 0; nf < 4; ++nf) {
      int n = n0 + wn * 64 + nf * 16 + h;
#pragma unroll
      for (int qq = 0; qq < 4; ++qq)
        Cks[(size_t)(mbase + qq) * 4096 + n] = acc[mf][nf][qq];
    }
  }
}

// ======================= Attention (MFMA, split bf16) ======================
__global__ __launch_bounds__(256) void attn_mfma_kernel(
    const unsigned short* __restrict__ qp, const unsigned short* __restrict__ kp,
    const unsigned short* __restrict__ vtp, const float* __restrict__ pos,
    unsigned short* __restrict__ Xp)
{
  __shared__ char smem[59904];
  unsigned short* qs = (unsigned short*)smem;
  unsigned short* kv = (unsigned short*)(smem + 8704);
  float* sc = (float*)(smem + 26112);
  unsigned short* ps = (unsigned short*)(smem + 26112);

  const int t = threadIdx.x;
  const int rt = blockIdx.x, cc = blockIdx.y, b = blockIdx.z;
  const int i0 = rt * 32;
  const size_t qkbase = (size_t)(b * 2 + cc) * 256;
  const size_t vbase  = (size_t)(b * 2 + cc) * 64;

  const int lane = t & 63, wvv = t >> 6;
  const int h = lane & 15, g = lane >> 4;

#pragma unroll
  for (int rep = 0; rep < 2; ++rep) {
    int s = t + rep * 256;
    int row = s >> 4;
    int blk = s & 15;
    int4 val = *(const int4*)(qp + (qkbase + i0 + row) * 128 + blk * 8);
    *(int4*)((char*)qs + row * 272 + blk * 16) = val;
  }

  for (int c = 0; c < 4; ++c) {
    __syncthreads();
#pragma unroll
    for (int p2 = 0; p2 < 4; ++p2) {
      int s = t + p2 * 256;
      int row = s >> 4;
      int blk = s & 15;
      int4 val = *(const int4*)(kp + (qkbase + c * 64 + row) * 128 + blk * 8);
      *(int4*)((char*)kv + row * 272 + blk * 16) = val;
    }
    __syncthreads();
    f32x4 acc2[2];
    acc2[0] = (f32x4){0.f, 0.f, 0.f, 0.f};
    acc2[1] = (f32x4){0.f, 0.f, 0.f, 0.f};
#pragma unroll
    for (int kk = 0; kk < 6; ++kk) {
      int abase = (kk < 2) ? kk * 32 : (kk < 4) ? 64 + (kk - 2) * 32 : (kk - 4) * 32;
      int bbase = (kk < 2) ? kk * 32 : (kk < 4) ? (kk - 2) * 32 : 64 + (kk - 4) * 32;
      s16x8 bfrag = *(const s16x8*)((char*)kv + (wvv * 16 + h) * 272 + (bbase + g * 8) * 2);
#pragma unroll
      for (int mf = 0; mf < 2; ++mf) {
        s16x8 afrag = *(const s16x8*)((char*)qs + (mf * 16 + h) * 272 + (abase + g * 8) * 2);
        acc2[mf] = __builtin_amdgcn_mfma_f32_16x16x32_bf16(afrag, bfrag, acc2[mf], 0, 0, 0);
      }
    }
#pragma unroll
    for (int mf = 0; mf < 2; ++mf)
#pragma unroll
      for (int qq = 0; qq < 4; ++qq) {
        int row = mf * 16 + g * 4 + qq;
        int j = c * 64 + wvv * 16 + h;
        sc[row * 264 + j] = acc2[mf][qq] * 0.125f +
            pos[((size_t)cc * 256 + i0 + row) * 256 + j];
      }
  }
  __syncthreads();

  {
    const int r = t >> 3, j8 = t & 7;
    float e[32];
    float mx = -3.4e38f;
#pragma unroll
    for (int jj = 0; jj < 32; ++jj) {
      e[jj] = sc[r * 264 + j8 + 8 * jj];
      mx = fmaxf(mx, e[jj]);
    }
#pragma unroll
    for (int mset = 1; mset < 8; mset <<= 1) mx = fmaxf(mx, __shfl_xor(mx, mset, 64));
    float sum = 0.f;
#pragma unroll
    for (int jj = 0; jj < 32; ++jj) {
      e[jj] = expf(e[jj] - mx);
      sum += e[jj];
    }
#pragma unroll
    for (int mset = 1; mset < 8; mset <<= 1) sum += __shfl_xor(sum, mset, 64);
    float inv = 1.f / sum;
    __syncthreads();
#pragma unroll
    for (int jj = 0; jj < 32; ++jj) {
      float pv = e[jj] * inv;
      unsigned short hi = f2bf(pv);
      unsigned short lo = f2bf(pv - bf2f(hi));
      int j = j8 + 8 * jj;
      ps[r * 528 + j] = hi;
      ps[r * 528 + 264 + j] = lo;
    }
  }

  f32x4 oacc[2];
  oacc[0] = (f32x4){0.f, 0.f, 0.f, 0.f};
  oacc[1] = (f32x4){0.f, 0.f, 0.f, 0.f};
  for (int c = 0; c < 4; ++c) {
    __syncthreads();
#pragma unroll
    for (int p2 = 0; p2 < 4; ++p2) {
      int s = t + p2 * 256, row = s >> 4, blk = s & 15;
      int col = (blk < 8) ? (c * 64 + blk * 8) : (256 + c * 64 + (blk - 8) * 8);
      int4 val = *(const int4*)(vtp + (vbase + row) * 512 + col);
      *(int4*)((char*)kv + row * 272 + blk * 16) = val;
    }
    __syncthreads();
#pragma unroll
    for (int kk = 0; kk < 6; ++kk) {
      int abase = (kk < 2) ? (c * 64 + kk * 32)
                : (kk < 4) ? (264 + c * 64 + (kk - 2) * 32)
                           : (c * 64 + (kk - 4) * 32);
      int bbase = (kk < 2) ? kk * 32 : (kk < 4) ? (kk - 2) * 32 : 64 + (kk - 4) * 32;
      s16x8 bfrag = *(const s16x8*)((char*)kv + (wvv * 16 + h) * 272 + (bbase + g * 8) * 2);
#pragma unroll
      for (int mf = 0; mf < 2; ++mf) {
        s16x8 afrag = *(const s16x8*)((char*)ps + (mf * 16 + h) * 1056 + (abase + g * 8) * 2);
        oacc[mf] = __builtin_amdgcn_mfma_f32_16x16x32_bf16(afrag, bfrag, oacc[mf], 0, 0, 0);
      }
    }
  }
  {
    int Xrow = b * 16 + cc * 8 + wvv * 2 + (h >> 3);
    int c7 = h & 7;
#pragma unroll
    for (int mf = 0; mf < 2; ++mf)
#pragma unroll
      for (int qq = 0; qq < 4; ++qq) {
        int dd = i0 + mf * 16 + g * 4 + qq;
        float vvv = oacc[mf][qq];
        unsigned short hi = f2bf(vvv);
        unsigned short lo = f2bf(vvv - bf2f(hi));
        size_t base = (size_t)Xrow * 4096 + dd * 8 + c7;
        Xp[base] = hi;
        Xp[base + 2048] = lo;
      }
  }
}

// ======================= epilogue: out = c1w*(G0+G1) + c1b*rs + lin_b =====
__global__ __launch_bounds__(256) void epilogue_kernel(
    const float* __restrict__ G, const float* __restrict__ rs,
    const float* __restrict__ c1w, const float* __restrict__ c1b,
    const float* __restrict__ linb, float* __restrict__ out)
{
  __shared__ float W[512];
  __shared__ float Bp[32];
  const int t = threadIdx.x;
  const int ntile = blockIdx.x;   // 0..15
  const int b = blockIdx.y;       // 0..63
  W[t] = c1w[t];
  W[t + 256] = c1w[t + 256];
  if (t < 32) Bp[t] = c1b[t];
  __syncthreads();
  const int n = ntile * 256 + t;
  float gv[16];
#pragma unroll
  for (int ch = 0; ch < 16; ++ch) {
    size_t off = (size_t)(b * 16 + ch) * 4096 + n;
    gv[ch] = G[off] + G[4194304 + off];
  }
  const float rsn = rs[n];
  const float lbn = linb[n];
#pragma unroll
  for (int o = 0; o < 32; ++o) {
    float s = lbn + Bp[o] * rsn;
#pragma unroll
    for (int ch = 0; ch < 16; ++ch) s = fmaf(W[o * 16 + ch], gv[ch], s);
    out[(size_t)(b * 32 + o) * 4096 + n] = s;
  }
}

// ======================= launch ============================================
extern "C" void kernel_launch(void* const* d_in, const int* in_sizes, int n_in,
                              void* d_out, int out_size, void* d_ws, size_t ws_size,
                              hipStream_t stream) {
  const float* q    = (const float*)d_in[0];
  const float* k    = (const float*)d_in[1];
  const float* v    = (const float*)d_in[2];
  const float* dwk  = (const float*)d_in[3];
  const float* bng  = (const float*)d_in[4];
  const float* bnb  = (const float*)d_in[5];
  const float* bnm  = (const float*)d_in[6];
  const float* bnv  = (const float*)d_in[7];
  const float* pwk  = (const float*)d_in[8];
  const float* pos  = (const float*)d_in[9];
  const float* c1w  = (const float*)d_in[10];
  const float* c1b  = (const float*)d_in[11];
  const float* linw = (const float*)d_in[12];
  const float* linb = (const float*)d_in[13];
  float* out = (float*)d_out;

  if (ws_size < 50331648u) return;

  char* ws = (char*)d_ws;
  unsigned short* qp   = (unsigned short*)(ws + 0);          //  8,388,608
  unsigned short* kpp  = (unsigned short*)(ws + 8388608);    //  8,388,608
  unsigned short* vtp  = (unsigned short*)(ws + 16777216);   //  8,388,608
  unsigned short* tTp  = (unsigned short*)(ws + 25165824);   // 25,165,824
  unsigned short* pwkp = (unsigned short*)d_out;             //  3,145,728 (d_out scratch)
  unsigned short* Xp   = (unsigned short*)(ws + 41943040);   //  8,388,608 (over tTp slab 2)
  float*          rs   = (float*)(ws + 0);                   //     16,384 (over qp)
  unsigned short* lwp  = (unsigned short*)d_out;             // 33,554,432 (d_out scratch)
  float*          G    = (float*)(ws + 8388608);             // 33,554,432 (G[2], over kpp/vtp/tTp01)

  // 1) split pointwise weights (into d_out scratch)
  split_kernel<<<768, 256, 0, stream>>>(pwk, pwkp, 9, 196608);

  // 2) dwconv+BN+GELU, all three inputs -> tTp
  stageA_kernel<<<dim3(1024, 3), 256, 0, stream>>>(
      q, k, v, dwk, bng, bnb, bnm, bnv, tTp);

  // 3) pointwise GEMMs (naive batched) -> qp/kpp/vtp
  gemm_split_kernel<<<dim3(32, 8, 3), 256, 0, stream>>>(
      pwkp, tTp, qp, 512, 4096, 512);

  // 4) attention -> X' split-bf16 @ws 41.9M (over tTp slab 2)
  attn_mfma_kernel<<<dim3(8, 2, 64), 256, 0, stream>>>(qp, kpp, vtp, pos, Xp);

  // 5) split linw (+ row sums) into d_out scratch / ws
  hipMemsetAsync(rs, 0, 16384, stream);
  split_rs_kernel<<<8192, 256, 0, stream>>>(linw, lwp, rs, 2097152);

  // 6) G[ks] = X' * lwp^T partials  (deep pipe, split-K, 256 blocks)
  gemm_final_kernel<<<dim3(32, 8), 512, 0, stream>>>(Xp, lwp, G);

  // 7) out = c1w*(G0+G1) + c1b*rs + lin_b
  epilogue_kernel<<<dim3(16, 64), 256, 0, stream>>>(G, rs, c1w, c1b, linb, out);
}

// Round 15
// 180.467 us; speedup vs baseline: 1.0742x; 1.0118x over previous
//
#include <hip/hip_runtime.h>

// ---------------------------------------------------------------------------
// Geometry: b=64, units=32, d_model=4096, P=16 -> c=2, d=256, C=512,
// dwconv 3x3 s2 16x16->8x8 (hw=64), dk=64; attn 256x256 per (b,cc).
//
// RESTRUCTURING: conv1d (16->32ch) and Linear (over l) commute:
//   out = c1w · (X · W^T) + c1b · rowsum(W) + lin_b
// big GEMM at M=1024; final GEMM = BM=256xBN=128 8-wave 4-phase 3-LDS-buffer
// pipe + split-K x2 (256 blocks); partials G[2] summed in the epilogue.
// Pointwise GEMM: 2-wave blocks, wave owns 64x64 (AI 2.0 MFMA/ds_read).
//
// All GEMM-shaped work runs as bf16 hi/lo split MFMA:
//   C = Ah*Bh + Ah*Bl + Al*Bh  (K' = 3K, error ~2^-17 rel).
//
// Workspace (ws = 48 MiB) / d_out (32 MiB) choreography:
//   1) pwkp -> d_out[0..3.1M]
//   2) tTp bf16 [3][4096][1024] @ws 25.2M..50.3M
//   3) qp @ws0, kpp @8.4M, vtp @16.8M  (pointwise GEMM)
//   4) attn -> Xp @ws 41.9M (over tTp slab 2)
//   5) split_rs (row-owned, no atomics): lwp -> d_out; rs @ws0 (over qp)
//   6) gemm_final reads Xp,lwp -> G[2] f32 @ws 8.4M..41.9M
//   7) epilogue reads G0+G1,rs,c1w,c1b,linb -> writes d_out (over lwp)
// ---------------------------------------------------------------------------

typedef short s16x8 __attribute__((ext_vector_type(8)));
typedef float f32x4 __attribute__((ext_vector_type(4)));
typedef const __attribute__((address_space(1))) void* gas_t;
typedef __attribute__((address_space(3))) void* las_t;

__device__ __forceinline__ unsigned short f2bf(float x) {
  unsigned u = __float_as_uint(x);
  unsigned r = u + 0x7fffu + ((u >> 16) & 1u);
  return (unsigned short)(r >> 16);
}
__device__ __forceinline__ float bf2f(unsigned short h) {
  return __uint_as_float((unsigned)h << 16);
}

// ======================= Stage A: patch + dwconv + BN + GELU (batched) =====
__global__ __launch_bounds__(256) void stageA_kernel(
    const float* __restrict__ xq, const float* __restrict__ xk,
    const float* __restrict__ xv, const float* __restrict__ dwk,
    const float* __restrict__ bng, const float* __restrict__ bnb,
    const float* __restrict__ bnm, const float* __restrict__ bnv,
    unsigned short* __restrict__ tTp)
{
  const int i  = blockIdx.y;
  const float* x = (i == 0) ? xq : (i == 1) ? xk : xv;
  const float* dwk_i = dwk + (size_t)i * 4608;
  const int co = i * 512;
  unsigned short* out = tTp + (size_t)i * 4194304;

  const int dd = threadIdx.x;
  const int oh = blockIdx.x & 7;
  const int cc = (blockIdx.x >> 3) & 1;
  const int b  = blockIdx.x >> 4;
  const int ch = cc * 256 + dd;

  float r[3][16];
#pragma unroll
  for (int kh = 0; kh < 3; ++kh) {
    int ih = 2 * oh - 1 + kh;
    if (ih >= 0 && ih <= 15) {
      const float* p = x + (size_t)(b * 32 + cc * 16 + ih) * 4096 + dd * 16;
#pragma unroll
      for (int jq = 0; jq < 4; ++jq)
        *(float4*)&r[kh][jq * 4] = *(const float4*)(p + jq * 4);
    } else {
#pragma unroll
      for (int j = 0; j < 16; ++j) r[kh][j] = 0.f;
    }
  }
  float w9[9];
#pragma unroll
  for (int j = 0; j < 9; ++j) w9[j] = dwk_i[ch * 9 + j];
  const float scale = bng[co + ch] / sqrtf(bnv[co + ch] + 1e-5f);
  const float shift = bnb[co + ch] - bnm[co + ch] * scale;

#pragma unroll
  for (int ow = 0; ow < 8; ++ow) {
    float acc = 0.f;
#pragma unroll
    for (int kh = 0; kh < 3; ++kh)
#pragma unroll
      for (int kw = 0; kw < 3; ++kw) {
        int iw = 2 * ow - 1 + kw;
        if (iw >= 0 && iw <= 15) acc = fmaf(r[kh][iw], w9[kh * 3 + kw], acc);
      }
    float y = acc * scale + shift;
    y = 0.5f * y * (1.f + erff(y * 0.70710678118654752f));
    unsigned short hi = f2bf(y);
    unsigned short lo = f2bf(y - bf2f(hi));
    size_t rowb = (size_t)(b * 64 + oh * 8 + ow) * 1024;
    out[rowb + ch] = hi;
    out[rowb + 512 + ch] = lo;
  }
}

// ======================= fp32 -> bf16 hi|lo split ==========================
__global__ __launch_bounds__(256) void split_kernel(
    const float* __restrict__ src, unsigned short* __restrict__ dst,
    int kshift, int total4)
{
  int i = blockIdx.x * 256 + threadIdx.x;
  if (i >= total4) return;
  size_t i4 = (size_t)i * 4;
  int K = 1 << kshift;
  int r = (int)(i4 >> kshift);
  int c = (int)(i4 & (size_t)(K - 1));
  float4 xv = *(const float4*)(src + i4);
  unsigned short h0 = f2bf(xv.x), h1 = f2bf(xv.y), h2 = f2bf(xv.z), h3 = f2bf(xv.w);
  unsigned short l0 = f2bf(xv.x - bf2f(h0)), l1 = f2bf(xv.y - bf2f(h1));
  unsigned short l2 = f2bf(xv.z - bf2f(h2)), l3 = f2bf(xv.w - bf2f(h3));
  unsigned short* dr = dst + (size_t)r * (K * 2) + c;
  uint2 hp, lp;
  hp.x = (unsigned)h0 | ((unsigned)h1 << 16);
  hp.y = (unsigned)h2 | ((unsigned)h3 << 16);
  lp.x = (unsigned)l0 | ((unsigned)l1 << 16);
  lp.y = (unsigned)l2 | ((unsigned)l3 << 16);
  *(uint2*)dr = hp;
  *(uint2*)(dr + K) = lp;
}

// ======================= split + row-sum (linw), row-owned, no atomics =====
// Block r (0..4095) owns one full linw row (2048 fp32). Thread t handles
// 8 elems. Writes lwp[r][0..2047]=hi, [2048..4095]=lo; rs[r] = row sum.
__global__ __launch_bounds__(256) void split_rs_kernel(
    const float* __restrict__ src, unsigned short* __restrict__ dst,
    float* __restrict__ rs)
{
  __shared__ float wsum[4];
  const int r = blockIdx.x;
  const int t = threadIdx.x;
  const float* rowp = src + (size_t)r * 2048 + t * 8;
  float4 x0 = *(const float4*)rowp;
  float4 x1 = *(const float4*)(rowp + 4);
  unsigned short h0 = f2bf(x0.x), h1 = f2bf(x0.y), h2 = f2bf(x0.z), h3 = f2bf(x0.w);
  unsigned short h4 = f2bf(x1.x), h5 = f2bf(x1.y), h6 = f2bf(x1.z), h7 = f2bf(x1.w);
  uint4 hp, lp;
  hp.x = (unsigned)h0 | ((unsigned)h1 << 16);
  hp.y = (unsigned)h2 | ((unsigned)h3 << 16);
  hp.z = (unsigned)h4 | ((unsigned)h5 << 16);
  hp.w = (unsigned)h6 | ((unsigned)h7 << 16);
  lp.x = (unsigned)f2bf(x0.x - bf2f(h0)) | ((unsigned)f2bf(x0.y - bf2f(h1)) << 16);
  lp.y = (unsigned)f2bf(x0.z - bf2f(h2)) | ((unsigned)f2bf(x0.w - bf2f(h3)) << 16);
  lp.z = (unsigned)f2bf(x1.x - bf2f(h4)) | ((unsigned)f2bf(x1.y - bf2f(h5)) << 16);
  lp.w = (unsigned)f2bf(x1.z - bf2f(h6)) | ((unsigned)f2bf(x1.w - bf2f(h7)) << 16);
  unsigned short* dr = dst + (size_t)r * 4096 + t * 8;
  *(uint4*)dr = hp;
  *(uint4*)(dr + 2048) = lp;
  float s = x0.x + x0.y + x0.z + x0.w + x1.x + x1.y + x1.z + x1.w;
#pragma unroll
  for (int off = 1; off < 64; off <<= 1) s += __shfl_xor(s, off, 64);
  if ((t & 63) == 0) wsum[t >> 6] = s;
  __syncthreads();
  if (t == 0) rs[r] = wsum[0] + wsum[1] + wsum[2] + wsum[3];
}

// ======================= pointwise: bf16-split MFMA NT GEMM (batched z=3) ==
// BM=64 x BN=128, 128 threads = 2 waves, each wave owns 64x64 (acc[4][4],
// 2.0 MFMA/ds_read). Naive 2-barrier loop, 24 K-tiles. Grid (32,8,3).
__global__ __launch_bounds__(128) void gemm_split_kernel(
    const unsigned short* __restrict__ Aall, const unsigned short* __restrict__ Ball,
    unsigned short* __restrict__ Call)
{
  __shared__ unsigned short sA[4096];    // [64][64]
  __shared__ unsigned short sB[8192];    // [128][64]
  const int t = threadIdx.x;             // 0..127
  const int z = blockIdx.z;
  const unsigned short* A = Aall + (size_t)z * 524288;    // [512][1024]
  const unsigned short* B = Ball + (size_t)z * 4194304;   // [4096][1024]
  unsigned short* Cq = Call + (size_t)z * 4194304;
  const int m0 = blockIdx.y * 64, n0 = blockIdx.x * 128;
  const int K = 512, twoK = 1024, Km = 511;
  const int lane = t & 63;
  const int wv = t >> 6;                 // 0..1
  const int colbase = wv * 64;
  const int h = lane & 15, g = lane >> 4;

  f32x4 acc[4][4];
#pragma unroll
  for (int mf = 0; mf < 4; ++mf)
#pragma unroll
    for (int nf = 0; nf < 4; ++nf)
      acc[mf][nf] = (f32x4){0.f, 0.f, 0.f, 0.f};

  int arow[4], ablk[4], brow[8], bblk[8];
#pragma unroll
  for (int it = 0; it < 4; ++it) {
    int s = it * 128 + t;
    arow[it] = s >> 3;
    ablk[it] = (s & 7) ^ (arow[it] & 7);
  }
#pragma unroll
  for (int it = 0; it < 8; ++it) {
    int s = it * 128 + t;
    brow[it] = s >> 3;
    bblk[it] = (s & 7) ^ (brow[it] & 7);
  }

  for (int k0 = 0; k0 < 1536; k0 += 64) {
    __syncthreads();
#pragma unroll
    for (int it = 0; it < 4; ++it) {
      int kp = k0 + ablk[it] * 8;
      int ac = (kp < twoK) ? (kp & Km) : (kp - K);
      __builtin_amdgcn_global_load_lds(
          (gas_t)(const void*)(A + (size_t)(m0 + arow[it]) * twoK + ac),
          (las_t)(void*)((char*)sA + (it * 2048 + t * 16)), 16, 0, 0);
    }
#pragma unroll
    for (int it = 0; it < 8; ++it) {
      int kp = k0 + bblk[it] * 8;
      int bc = (kp < twoK) ? kp : (kp - twoK);
      __builtin_amdgcn_global_load_lds(
          (gas_t)(const void*)(B + (size_t)(n0 + brow[it]) * twoK + bc),
          (las_t)(void*)((char*)sB + (it * 2048 + t * 16)), 16, 0, 0);
    }
    __syncthreads();

#pragma unroll
    for (int kk = 0; kk < 2; ++kk) {
      s16x8 af[4], bfr[4];
#pragma unroll
      for (int mf = 0; mf < 4; ++mf) {
        int aoff = (mf * 16 + h) * 128 + (((kk * 4 + g) ^ (h & 7)) << 4);
        af[mf] = *(const s16x8*)((const char*)sA + aoff);
      }
#pragma unroll
      for (int nf = 0; nf < 4; ++nf) {
        int boff = (colbase + nf * 16 + h) * 128 + (((kk * 4 + g) ^ (h & 7)) << 4);
        bfr[nf] = *(const s16x8*)((const char*)sB + boff);
      }
#pragma unroll
      for (int mf = 0; mf < 4; ++mf)
#pragma unroll
        for (int nf = 0; nf < 4; ++nf)
          acc[mf][nf] = __builtin_amdgcn_mfma_f32_16x16x32_bf16(
              af[mf], bfr[nf], acc[mf][nf], 0, 0, 0);
    }
  }

  if (z < 2) {
    // Q'/K' layout: rows = attention row index (ch%256), cols = d hi|lo
#pragma unroll
    for (int mf = 0; mf < 4; ++mf) {
      int mbase = m0 + mf * 16 + g * 4;
#pragma unroll
      for (int nf = 0; nf < 4; ++nf) {
        int n = n0 + colbase + nf * 16 + h;
        int bb = n >> 6, d = n & 63;
#pragma unroll
        for (int qq = 0; qq < 4; ++qq) {
          int m = mbase + qq;
          int cc = m >> 8;
          size_t rowb = ((size_t)(bb * 2 + cc) * 256 + (m & 255)) * 128;
          float vvv = acc[mf][nf][qq];
          unsigned short hi = f2bf(vvv);
          unsigned short lo = f2bf(vvv - bf2f(hi));
          Cq[rowb + d] = hi;
          Cq[rowb + 64 + d] = lo;
        }
      }
    }
  } else {
    // V^T layout: rows = d, cols = j hi|lo
#pragma unroll
    for (int mf = 0; mf < 4; ++mf) {
      int mbase = m0 + mf * 16 + g * 4;
      int cc = mbase >> 8;
      int mc = mbase & 255;
#pragma unroll
      for (int nf = 0; nf < 4; ++nf) {
        int n = n0 + colbase + nf * 16 + h;
        int bb = n >> 6, d = n & 63;
        size_t rowb = ((size_t)(bb * 2 + cc) * 64 + d) * 512;
        ushort4 hv, lv;
        float v0 = acc[mf][nf][0], v1 = acc[mf][nf][1];
        float v2 = acc[mf][nf][2], v3 = acc[mf][nf][3];
        hv.x = f2bf(v0); hv.y = f2bf(v1); hv.z = f2bf(v2); hv.w = f2bf(v3);
        lv.x = f2bf(v0 - bf2f(hv.x)); lv.y = f2bf(v1 - bf2f(hv.y));
        lv.z = f2bf(v2 - bf2f(hv.z)); lv.w = f2bf(v3 - bf2f(hv.w));
        *(ushort4*)&Cq[rowb + mc] = hv;
        *(ushort4*)&Cq[rowb + 256 + mc] = lv;
      }
    }
  }
}

// ======================= final GEMM: deep pipe + split-K ===================
// G[ks] = X'(1024x4096) * lwp^T over K'-half. BM=256, BN=128, BK=64,
// 8 waves, 4x4 16x16 frags/wave, 3 LDS buffers (147KB), 4 phases/K-tile,
// counted vmcnt(6). Grid (32,8) ONLY (hardcoded swizzle).
__global__ __launch_bounds__(512, 2) void gemm_final_kernel(
    const unsigned short* __restrict__ A, const unsigned short* __restrict__ B,
    float* __restrict__ C)
{
  __shared__ unsigned short lds[73728];    // 147456 B = 3 x 49152
  const int t = threadIdx.x;

  const int flat = blockIdx.y * 32 + blockIdx.x;  // 0..255
  const int xcd = flat & 7;
  const int ii = flat >> 3;                 // 0..31
  const int n0 = (xcd * 4 + (ii & 3)) * 128;
  const int rem = ii >> 2;                  // 0..7
  const int m0 = (rem & 3) * 256;
  const int ks = rem >> 2;                  // 0..1
  const int base = ks * 48;

  const int K = 2048, twoK = 4096, Km = 2047;

  const int lane = t & 63;
  const int wv = t >> 6;
  const int wm = wv & 3, wn = wv >> 2;
  const int h = lane & 15, g = lane >> 4;

  f32x4 acc[4][4];
#pragma unroll
  for (int mf = 0; mf < 4; ++mf)
#pragma unroll
    for (int nf = 0; nf < 4; ++nf)
      acc[mf][nf] = (f32x4){0.f, 0.f, 0.f, 0.f};

  int arow[4], ablk[4], brow[2], bblk[2];
#pragma unroll
  for (int it = 0; it < 4; ++it) {
    int s = it * 512 + t;
    arow[it] = s >> 3;
    ablk[it] = (t & 7) ^ (arow[it] & 7);
  }
#pragma unroll
  for (int it = 0; it < 2; ++it) {
    int s = it * 512 + t;
    brow[it] = s >> 3;
    bblk[it] = (t & 7) ^ (brow[it] & 7);
  }

  auto issueA = [&](int buf, int tt, int it) {
    int kp = tt * 64 + ablk[it] * 8;
    int ac = (kp < twoK) ? (kp & Km) : (kp - K);
    __builtin_amdgcn_global_load_lds(
        (gas_t)(const void*)(A + (size_t)(m0 + arow[it]) * twoK + ac),
        (las_t)(void*)((char*)lds + (buf * 49152 + it * 8192 + t * 16)), 16, 0, 0);
  };
  auto issueB = [&](int buf, int tt, int it) {
    int kp = tt * 64 + bblk[it] * 8;
    int bc = (kp < twoK) ? kp : (kp - twoK);
    __builtin_amdgcn_global_load_lds(
        (gas_t)(const void*)(B + (size_t)(n0 + brow[it]) * twoK + bc),
        (las_t)(void*)((char*)lds + (buf * 49152 + 32768 + it * 8192 + t * 16)), 16, 0, 0);
  };

  const int aoffb = (wm * 64 + h) * 128;
  const int boffb = 32768 + (wn * 64 + h) * 128;
  int colx[2];
  colx[0] = ((g) ^ (h & 7)) << 4;
  colx[1] = ((4 + g) ^ (h & 7)) << 4;

  auto rdA = [&](int buf, int kk, int mf) -> s16x8 {
    return *(const s16x8*)((const char*)lds + (buf * 49152 + aoffb + mf * 2048 + colx[kk]));
  };
  auto rdB = [&](int buf, int kk, int nf) -> s16x8 {
    return *(const s16x8*)((const char*)lds + (buf * 49152 + boffb + nf * 2048 + colx[kk]));
  };

#define MFMA_ROW2(A0, A1, A2, A3, BB, NF) \
  acc[0][NF] = __builtin_amdgcn_mfma_f32_16x16x32_bf16(A0, BB, acc[0][NF], 0, 0, 0); \
  acc[1][NF] = __builtin_amdgcn_mfma_f32_16x16x32_bf16(A1, BB, acc[1][NF], 0, 0, 0); \
  acc[2][NF] = __builtin_amdgcn_mfma_f32_16x16x32_bf16(A2, BB, acc[2][NF], 0, 0, 0); \
  acc[3][NF] = __builtin_amdgcn_mfma_f32_16x16x32_bf16(A3, BB, acc[3][NF], 0, 0, 0);

#pragma unroll
  for (int it = 0; it < 4; ++it) issueA(0, base, it);
#pragma unroll
  for (int it = 0; it < 2; ++it) issueB(0, base, it);
#pragma unroll
  for (int it = 0; it < 4; ++it) issueA(1, base + 1, it);
#pragma unroll
  for (int it = 0; it < 2; ++it) issueB(1, base + 1, it);
  asm volatile("s_waitcnt vmcnt(6)" ::: "memory");
  __builtin_amdgcn_sched_barrier(0);
  __builtin_amdgcn_s_barrier();
  __builtin_amdgcn_sched_barrier(0);

  int bR = 0;
  for (int tt = base; tt <= base + 45; ++tt) {
    const int bn2 = (bR >= 1) ? bR - 1 : 2;      // (bR+2)%3
    s16x8 a0 = rdA(bR, 0, 0), a1 = rdA(bR, 0, 1), a2 = rdA(bR, 0, 2), a3 = rdA(bR, 0, 3);
    s16x8 b0 = rdB(bR, 0, 0), b1 = rdB(bR, 0, 1);
    issueA(bn2, tt + 2, 0); issueA(bn2, tt + 2, 1);
    __builtin_amdgcn_s_barrier();
    __builtin_amdgcn_s_setprio(1);
    MFMA_ROW2(a0, a1, a2, a3, b0, 0)
    MFMA_ROW2(a0, a1, a2, a3, b1, 1)
    __builtin_amdgcn_s_setprio(0);
    __builtin_amdgcn_s_barrier();
    s16x8 b2 = rdB(bR, 0, 2), b3 = rdB(bR, 0, 3);
    issueA(bn2, tt + 2, 2); issueA(bn2, tt + 2, 3);
    __builtin_amdgcn_s_barrier();
    __builtin_amdgcn_s_setprio(1);
    MFMA_ROW2(a0, a1, a2, a3, b2, 2)
    MFMA_ROW2(a0, a1, a2, a3, b3, 3)
    __builtin_amdgcn_s_setprio(0);
    __builtin_amdgcn_s_barrier();
    a0 = rdA(bR, 1, 0); a1 = rdA(bR, 1, 1); a2 = rdA(bR, 1, 2); a3 = rdA(bR, 1, 3);
    b0 = rdB(bR, 1, 0); b1 = rdB(bR, 1, 1);
    issueB(bn2, tt + 2, 0);
    __builtin_amdgcn_s_barrier();
    __builtin_amdgcn_s_setprio(1);
    MFMA_ROW2(a0, a1, a2, a3, b0, 0)
    MFMA_ROW2(a0, a1, a2, a3, b1, 1)
    __builtin_amdgcn_s_setprio(0);
    __builtin_amdgcn_s_barrier();
    b2 = rdB(bR, 1, 2); b3 = rdB(bR, 1, 3);
    issueB(bn2, tt + 2, 1);
    __builtin_amdgcn_s_barrier();
    __builtin_amdgcn_s_setprio(1);
    MFMA_ROW2(a0, a1, a2, a3, b2, 2)
    MFMA_ROW2(a0, a1, a2, a3, b3, 3)
    __builtin_amdgcn_s_setprio(0);
    asm volatile("s_waitcnt vmcnt(6)" ::: "memory");
    __builtin_amdgcn_sched_barrier(0);
    __builtin_amdgcn_s_barrier();
    __builtin_amdgcn_sched_barrier(0);
    bR = (bR == 2) ? 0 : bR + 1;
  }

  auto compute_tile = [&](int buf) {
#pragma unroll
    for (int kk = 0; kk < 2; ++kk) {
      s16x8 ta0 = rdA(buf, kk, 0), ta1 = rdA(buf, kk, 1);
      s16x8 ta2 = rdA(buf, kk, 2), ta3 = rdA(buf, kk, 3);
      s16x8 tb0 = rdB(buf, kk, 0), tb1 = rdB(buf, kk, 1);
      s16x8 tb2 = rdB(buf, kk, 2), tb3 = rdB(buf, kk, 3);
      MFMA_ROW2(ta0, ta1, ta2, ta3, tb0, 0)
      MFMA_ROW2(ta0, ta1, ta2, ta3, tb1, 1)
      MFMA_ROW2(ta0, ta1, ta2, ta3, tb2, 2)
      MFMA_ROW2(ta0, ta1, ta2, ta3, tb3, 3)
    }
  };
  compute_tile(bR);
  __syncthreads();
  compute_tile((bR == 2) ? 0 : bR + 1);
#undef MFMA_ROW2

  float* Cks = C + (size_t)ks * 4194304;
#pragma unroll
  for (int mf = 0; mf < 4; ++mf) {
    int mbase = m0 + wm * 64 + mf * 16 + g * 4;
#pragma unroll
    for (int nf = 0; nf < 4; ++nf) {
      int n = n0 + wn * 64 + nf * 16 + h;
#pragma unroll
      for (int qq = 0; qq < 4; ++qq)
        Cks[(size_t)(mbase + qq) * 4096 + n] = acc[mf][nf][qq];
    }
  }
}

// ======================= Attention (MFMA, split bf16) ======================
__global__ __launch_bounds__(256) void attn_mfma_kernel(
    const unsigned short* __restrict__ qp, const unsigned short* __restrict__ kp,
    const unsigned short* __restrict__ vtp, const float* __restrict__ pos,
    unsigned short* __restrict__ Xp)
{
  __shared__ char smem[59904];
  unsigned short* qs = (unsigned short*)smem;
  unsigned short* kv = (unsigned short*)(smem + 8704);
  float* sc = (float*)(smem + 26112);
  unsigned short* ps = (unsigned short*)(smem + 26112);

  const int t = threadIdx.x;
  const int rt = blockIdx.x, cc = blockIdx.y, b = blockIdx.z;
  const int i0 = rt * 32;
  const size_t qkbase = (size_t)(b * 2 + cc) * 256;
  const size_t vbase  = (size_t)(b * 2 + cc) * 64;

  const int lane = t & 63, wvv = t >> 6;
  const int h = lane & 15, g = lane >> 4;

#pragma unroll
  for (int rep = 0; rep < 2; ++rep) {
    int s = t + rep * 256;
    int row = s >> 4;
    int blk = s & 15;
    int4 val = *(const int4*)(qp + (qkbase + i0 + row) * 128 + blk * 8);
    *(int4*)((char*)qs + row * 272 + blk * 16) = val;
  }

  for (int c = 0; c < 4; ++c) {
    __syncthreads();
#pragma unroll
    for (int p2 = 0; p2 < 4; ++p2) {
      int s = t + p2 * 256;
      int row = s >> 4;
      int blk = s & 15;
      int4 val = *(const int4*)(kp + (qkbase + c * 64 + row) * 128 + blk * 8);
      *(int4*)((char*)kv + row * 272 + blk * 16) = val;
    }
    __syncthreads();
    f32x4 acc2[2];
    acc2[0] = (f32x4){0.f, 0.f, 0.f, 0.f};
    acc2[1] = (f32x4){0.f, 0.f, 0.f, 0.f};
#pragma unroll
    for (int kk = 0; kk < 6; ++kk) {
      int abase = (kk < 2) ? kk * 32 : (kk < 4) ? 64 + (kk - 2) * 32 : (kk - 4) * 32;
      int bbase = (kk < 2) ? kk * 32 : (kk < 4) ? (kk - 2) * 32 : 64 + (kk - 4) * 32;
      s16x8 bfrag = *(const s16x8*)((char*)kv + (wvv * 16 + h) * 272 + (bbase + g * 8) * 2);
#pragma unroll
      for (int mf = 0; mf < 2; ++mf) {
        s16x8 afrag = *(const s16x8*)((char*)qs + (mf * 16 + h) * 272 + (abase + g * 8) * 2);
        acc2[mf] = __builtin_amdgcn_mfma_f32_16x16x32_bf16(afrag, bfrag, acc2[mf], 0, 0, 0);
      }
    }
#pragma unroll
    for (int mf = 0; mf < 2; ++mf)
#pragma unroll
      for (int qq = 0; qq < 4; ++qq) {
        int row = mf * 16 + g * 4 + qq;
        int j = c * 64 + wvv * 16 + h;
        sc[row * 264 + j] = acc2[mf][qq] * 0.125f +
            pos[((size_t)cc * 256 + i0 + row) * 256 + j];
      }
  }
  __syncthreads();

  {
    const int r = t >> 3, j8 = t & 7;
    float e[32];
    float mx = -3.4e38f;
#pragma unroll
    for (int jj = 0; jj < 32; ++jj) {
      e[jj] = sc[r * 264 + j8 + 8 * jj];
      mx = fmaxf(mx, e[jj]);
    }
#pragma unroll
    for (int mset = 1; mset < 8; mset <<= 1) mx = fmaxf(mx, __shfl_xor(mx, mset, 64));
    float sum = 0.f;
#pragma unroll
    for (int jj = 0; jj < 32; ++jj) {
      e[jj] = expf(e[jj] - mx);
      sum += e[jj];
    }
#pragma unroll
    for (int mset = 1; mset < 8; mset <<= 1) sum += __shfl_xor(sum, mset, 64);
    float inv = 1.f / sum;
    __syncthreads();
#pragma unroll
    for (int jj = 0; jj < 32; ++jj) {
      float pv = e[jj] * inv;
      unsigned short hi = f2bf(pv);
      unsigned short lo = f2bf(pv - bf2f(hi));
      int j = j8 + 8 * jj;
      ps[r * 528 + j] = hi;
      ps[r * 528 + 264 + j] = lo;
    }
  }

  f32x4 oacc[2];
  oacc[0] = (f32x4){0.f, 0.f, 0.f, 0.f};
  oacc[1] = (f32x4){0.f, 0.f, 0.f, 0.f};
  for (int c = 0; c < 4; ++c) {
    __syncthreads();
#pragma unroll
    for (int p2 = 0; p2 < 4; ++p2) {
      int s = t + p2 * 256, row = s >> 4, blk = s & 15;
      int col = (blk < 8) ? (c * 64 + blk * 8) : (256 + c * 64 + (blk - 8) * 8);
      int4 val = *(const int4*)(vtp + (vbase + row) * 512 + col);
      *(int4*)((char*)kv + row * 272 + blk * 16) = val;
    }
    __syncthreads();
#pragma unroll
    for (int kk = 0; kk < 6; ++kk) {
      int abase = (kk < 2) ? (c * 64 + kk * 32)
                : (kk < 4) ? (264 + c * 64 + (kk - 2) * 32)
                           : (c * 64 + (kk - 4) * 32);
      int bbase = (kk < 2) ? kk * 32 : (kk < 4) ? (kk - 2) * 32 : 64 + (kk - 4) * 32;
      s16x8 bfrag = *(const s16x8*)((char*)kv + (wvv * 16 + h) * 272 + (bbase + g * 8) * 2);
#pragma unroll
      for (int mf = 0; mf < 2; ++mf) {
        s16x8 afrag = *(const s16x8*)((char*)ps + (mf * 16 + h) * 1056 + (abase + g * 8) * 2);
        oacc[mf] = __builtin_amdgcn_mfma_f32_16x16x32_bf16(afrag, bfrag, oacc[mf], 0, 0, 0);
      }
    }
  }
  {
    int Xrow = b * 16 + cc * 8 + wvv * 2 + (h >> 3);
    int c7 = h & 7;
#pragma unroll
    for (int mf = 0; mf < 2; ++mf)
#pragma unroll
      for (int qq = 0; qq < 4; ++qq) {
        int dd = i0 + mf * 16 + g * 4 + qq;
        float vvv = oacc[mf][qq];
        unsigned short hi = f2bf(vvv);
        unsigned short lo = f2bf(vvv - bf2f(hi));
        size_t base = (size_t)Xrow * 4096 + dd * 8 + c7;
        Xp[base] = hi;
        Xp[base + 2048] = lo;
      }
  }
}

// ======================= epilogue: out = c1w*(G0+G1) + c1b*rs + lin_b =====
__global__ __launch_bounds__(256) void epilogue_kernel(
    const float* __restrict__ G, const float* __restrict__ rs,
    const float* __restrict__ c1w, const float* __restrict__ c1b,
    const float* __restrict__ linb, float* __restrict__ out)
{
  __shared__ float W[512];
  __shared__ float Bp[32];
  const int t = threadIdx.x;
  const int ntile = blockIdx.x;   // 0..15
  const int b = blockIdx.y;       // 0..63
  W[t] = c1w[t];
  W[t + 256] = c1w[t + 256];
  if (t < 32) Bp[t] = c1b[t];
  __syncthreads();
  const int n = ntile * 256 + t;
  float gv[16];
#pragma unroll
  for (int ch = 0; ch < 16; ++ch) {
    size_t off = (size_t)(b * 16 + ch) * 4096 + n;
    gv[ch] = G[off] + G[4194304 + off];
  }
  const float rsn = rs[n];
  const float lbn = linb[n];
#pragma unroll
  for (int o = 0; o < 32; ++o) {
    float s = lbn + Bp[o] * rsn;
#pragma unroll
    for (int ch = 0; ch < 16; ++ch) s = fmaf(W[o * 16 + ch], gv[ch], s);
    out[(size_t)(b * 32 + o) * 4096 + n] = s;
  }
}

// ======================= launch ============================================
extern "C" void kernel_launch(void* const* d_in, const int* in_sizes, int n_in,
                              void* d_out, int out_size, void* d_ws, size_t ws_size,
                              hipStream_t stream) {
  const float* q    = (const float*)d_in[0];
  const float* k    = (const float*)d_in[1];
  const float* v    = (const float*)d_in[2];
  const float* dwk  = (const float*)d_in[3];
  const float* bng  = (const float*)d_in[4];
  const float* bnb  = (const float*)d_in[5];
  const float* bnm  = (const float*)d_in[6];
  const float* bnv  = (const float*)d_in[7];
  const float* pwk  = (const float*)d_in[8];
  const float* pos  = (const float*)d_in[9];
  const float* c1w  = (const float*)d_in[10];
  const float* c1b  = (const float*)d_in[11];
  const float* linw = (const float*)d_in[12];
  const float* linb = (const float*)d_in[13];
  float* out = (float*)d_out;

  if (ws_size < 50331648u) return;

  char* ws = (char*)d_ws;
  unsigned short* qp   = (unsigned short*)(ws + 0);          //  8,388,608
  unsigned short* kpp  = (unsigned short*)(ws + 8388608);    //  8,388,608
  unsigned short* vtp  = (unsigned short*)(ws + 16777216);   //  8,388,608
  unsigned short* tTp  = (unsigned short*)(ws + 25165824);   // 25,165,824
  unsigned short* pwkp = (unsigned short*)d_out;             //  3,145,728 (d_out scratch)
  unsigned short* Xp   = (unsigned short*)(ws + 41943040);   //  8,388,608 (over tTp slab 2)
  float*          rs   = (float*)(ws + 0);                   //     16,384 (over qp)
  unsigned short* lwp  = (unsigned short*)d_out;             // 33,554,432 (d_out scratch)
  float*          G    = (float*)(ws + 8388608);             // 33,554,432 (G[2])

  // 1) split pointwise weights (into d_out scratch)
  split_kernel<<<768, 256, 0, stream>>>(pwk, pwkp, 9, 196608);

  // 2) dwconv+BN+GELU, all three inputs -> tTp
  stageA_kernel<<<dim3(1024, 3), 256, 0, stream>>>(
      q, k, v, dwk, bng, bnb, bnm, bnv, tTp);

  // 3) pointwise GEMMs (2-wave, 64x64/wave) -> qp/kpp/vtp
  gemm_split_kernel<<<dim3(32, 8, 3), 128, 0, stream>>>(pwkp, tTp, qp);

  // 4) attention -> X' split-bf16 @ws 41.9M (over tTp slab 2)
  attn_mfma_kernel<<<dim3(8, 2, 64), 256, 0, stream>>>(qp, kpp, vtp, pos, Xp);

  // 5) split linw (+ row sums, no atomics) into d_out scratch / ws
  split_rs_kernel<<<4096, 256, 0, stream>>>(linw, lwp, rs);

  // 6) G[ks] = X' * lwp^T partials  (deep pipe, split-K, 256 blocks)
  gemm_final_kernel<<<dim3(32, 8), 512, 0, stream>>>(Xp, lwp, G);

  // 7) out = c1w*(G0+G1) + c1b*rs + lin_b
  epilogue_kernel<<<dim3(16, 64), 256, 0, stream>>>(G, rs, c1w, c1b, linb, out);
}

// Round 16
// 175.644 us; speedup vs baseline: 1.1037x; 1.0275x over previous
//
#include <hip/hip_runtime.h>

// ---------------------------------------------------------------------------
// Geometry: b=64, units=32, d_model=4096, P=16 -> c=2, d=256, C=512,
// dwconv 3x3 s2 16x16->8x8 (hw=64), dk=64; attn 256x256 per (b,cc).
//
// RESTRUCTURING: conv1d (16->32ch) and Linear (over l) commute:
//   out = c1w · (X · W^T) + c1b · rowsum(W) + lin_b
// big GEMM at M=1024; final GEMM = BM=256xBN=128 8-wave 4-phase 3-LDS-buffer
// pipe + split-K x2 (256 blocks); partials G[2] summed in the epilogue.
//
// All GEMM-shaped work runs as bf16 hi/lo split MFMA:
//   C = Ah*Bh + Ah*Bl + Al*Bh  (K' = 3K, error ~2^-17 rel).
//
// LAUNCH FUSION (5 kernels): pwk-split rides stageA's grid (y==3);
// linw split+rowsum rides attn's grid (z>=64).
//
// Workspace (ws = 48 MiB) / d_out (32 MiB) choreography:
//   1) stageA+split: tTp bf16 [3][4096][1024] @ws 25.2M..50.3M;
//      pwkp -> d_out[0..3.1M]
//   2) pointwise GEMM: qp @ws0, kpp @8.4M, vtp @16.8M
//   3) attn+split_rs: Xp @ws 41.9M (over tTp slab 2); lwp -> d_out;
//      rs @ws 33.5M (tTp slab-1 tail, untouched by attn)
//   4) gemm_final reads Xp,lwp -> G[2] f32 @ws 0..33.5M (over qp/kpp/vtp/slab0)
//   5) epilogue reads G0+G1,rs,c1w,c1b,linb -> writes d_out (over lwp)
// ---------------------------------------------------------------------------

typedef short s16x8 __attribute__((ext_vector_type(8)));
typedef float f32x4 __attribute__((ext_vector_type(4)));
typedef const __attribute__((address_space(1))) void* gas_t;
typedef __attribute__((address_space(3))) void* las_t;

__device__ __forceinline__ unsigned short f2bf(float x) {
  unsigned u = __float_as_uint(x);
  unsigned r = u + 0x7fffu + ((u >> 16) & 1u);
  return (unsigned short)(r >> 16);
}
__device__ __forceinline__ float bf2f(unsigned short h) {
  return __uint_as_float((unsigned)h << 16);
}

// ======== Stage A (y<3): patch+dwconv+BN+GELU | (y==3): pwk split ==========
__global__ __launch_bounds__(256) void stageA_split_kernel(
    const float* __restrict__ xq, const float* __restrict__ xk,
    const float* __restrict__ xv, const float* __restrict__ dwk,
    const float* __restrict__ bng, const float* __restrict__ bnb,
    const float* __restrict__ bnm, const float* __restrict__ bnv,
    unsigned short* __restrict__ tTp,
    const float* __restrict__ pwk, unsigned short* __restrict__ pwkp)
{
  if (blockIdx.y == 3) {
    // pwk split: [1536][512] fp32 -> pwkp [1536][1024] hi|lo (kshift=9)
    int i = blockIdx.x * 256 + threadIdx.x;
    if (i >= 196608) return;
    size_t i4 = (size_t)i * 4;
    int r = (int)(i4 >> 9);
    int c = (int)(i4 & 511);
    float4 xv4 = *(const float4*)(pwk + i4);
    unsigned short h0 = f2bf(xv4.x), h1 = f2bf(xv4.y), h2 = f2bf(xv4.z), h3 = f2bf(xv4.w);
    unsigned short l0 = f2bf(xv4.x - bf2f(h0)), l1 = f2bf(xv4.y - bf2f(h1));
    unsigned short l2 = f2bf(xv4.z - bf2f(h2)), l3 = f2bf(xv4.w - bf2f(h3));
    unsigned short* dr = pwkp + (size_t)r * 1024 + c;
    uint2 hp, lp;
    hp.x = (unsigned)h0 | ((unsigned)h1 << 16);
    hp.y = (unsigned)h2 | ((unsigned)h3 << 16);
    lp.x = (unsigned)l0 | ((unsigned)l1 << 16);
    lp.y = (unsigned)l2 | ((unsigned)l3 << 16);
    *(uint2*)dr = hp;
    *(uint2*)(dr + 512) = lp;
    return;
  }

  const int i  = blockIdx.y;
  const float* x = (i == 0) ? xq : (i == 1) ? xk : xv;
  const float* dwk_i = dwk + (size_t)i * 4608;
  const int co = i * 512;
  unsigned short* out = tTp + (size_t)i * 4194304;

  const int dd = threadIdx.x;
  const int oh = blockIdx.x & 7;
  const int cc = (blockIdx.x >> 3) & 1;
  const int b  = blockIdx.x >> 4;
  const int ch = cc * 256 + dd;

  float r[3][16];
#pragma unroll
  for (int kh = 0; kh < 3; ++kh) {
    int ih = 2 * oh - 1 + kh;
    if (ih >= 0 && ih <= 15) {
      const float* p = x + (size_t)(b * 32 + cc * 16 + ih) * 4096 + dd * 16;
#pragma unroll
      for (int jq = 0; jq < 4; ++jq)
        *(float4*)&r[kh][jq * 4] = *(const float4*)(p + jq * 4);
    } else {
#pragma unroll
      for (int j = 0; j < 16; ++j) r[kh][j] = 0.f;
    }
  }
  float w9[9];
#pragma unroll
  for (int j = 0; j < 9; ++j) w9[j] = dwk_i[ch * 9 + j];
  const float scale = bng[co + ch] / sqrtf(bnv[co + ch] + 1e-5f);
  const float shift = bnb[co + ch] - bnm[co + ch] * scale;

#pragma unroll
  for (int ow = 0; ow < 8; ++ow) {
    float acc = 0.f;
#pragma unroll
    for (int kh = 0; kh < 3; ++kh)
#pragma unroll
      for (int kw = 0; kw < 3; ++kw) {
        int iw = 2 * ow - 1 + kw;
        if (iw >= 0 && iw <= 15) acc = fmaf(r[kh][iw], w9[kh * 3 + kw], acc);
      }
    float y = acc * scale + shift;
    y = 0.5f * y * (1.f + erff(y * 0.70710678118654752f));
    unsigned short hi = f2bf(y);
    unsigned short lo = f2bf(y - bf2f(hi));
    size_t rowb = (size_t)(b * 64 + oh * 8 + ow) * 1024;
    out[rowb + ch] = hi;
    out[rowb + 512 + ch] = lo;
  }
}

// ======================= pointwise: bf16-split MFMA NT GEMM (batched z=3) ==
// BM=64 x BN=128, 128 threads = 2 waves, each wave owns 64x64 (acc[4][4]).
__global__ __launch_bounds__(128) void gemm_split_kernel(
    const unsigned short* __restrict__ Aall, const unsigned short* __restrict__ Ball,
    unsigned short* __restrict__ Call)
{
  __shared__ unsigned short sA[4096];    // [64][64]
  __shared__ unsigned short sB[8192];    // [128][64]
  const int t = threadIdx.x;             // 0..127
  const int z = blockIdx.z;
  const unsigned short* A = Aall + (size_t)z * 524288;    // [512][1024]
  const unsigned short* B = Ball + (size_t)z * 4194304;   // [4096][1024]
  unsigned short* Cq = Call + (size_t)z * 4194304;
  const int m0 = blockIdx.y * 64, n0 = blockIdx.x * 128;
  const int K = 512, twoK = 1024, Km = 511;
  const int lane = t & 63;
  const int wv = t >> 6;                 // 0..1
  const int colbase = wv * 64;
  const int h = lane & 15, g = lane >> 4;

  f32x4 acc[4][4];
#pragma unroll
  for (int mf = 0; mf < 4; ++mf)
#pragma unroll
    for (int nf = 0; nf < 4; ++nf)
      acc[mf][nf] = (f32x4){0.f, 0.f, 0.f, 0.f};

  int arow[4], ablk[4], brow[8], bblk[8];
#pragma unroll
  for (int it = 0; it < 4; ++it) {
    int s = it * 128 + t;
    arow[it] = s >> 3;
    ablk[it] = (s & 7) ^ (arow[it] & 7);
  }
#pragma unroll
  for (int it = 0; it < 8; ++it) {
    int s = it * 128 + t;
    brow[it] = s >> 3;
    bblk[it] = (s & 7) ^ (brow[it] & 7);
  }

  for (int k0 = 0; k0 < 1536; k0 += 64) {
    __syncthreads();
#pragma unroll
    for (int it = 0; it < 4; ++it) {
      int kp = k0 + ablk[it] * 8;
      int ac = (kp < twoK) ? (kp & Km) : (kp - K);
      __builtin_amdgcn_global_load_lds(
          (gas_t)(const void*)(A + (size_t)(m0 + arow[it]) * twoK + ac),
          (las_t)(void*)((char*)sA + (it * 2048 + t * 16)), 16, 0, 0);
    }
#pragma unroll
    for (int it = 0; it < 8; ++it) {
      int kp = k0 + bblk[it] * 8;
      int bc = (kp < twoK) ? kp : (kp - twoK);
      __builtin_amdgcn_global_load_lds(
          (gas_t)(const void*)(B + (size_t)(n0 + brow[it]) * twoK + bc),
          (las_t)(void*)((char*)sB + (it * 2048 + t * 16)), 16, 0, 0);
    }
    __syncthreads();

#pragma unroll
    for (int kk = 0; kk < 2; ++kk) {
      s16x8 af[4], bfr[4];
#pragma unroll
      for (int mf = 0; mf < 4; ++mf) {
        int aoff = (mf * 16 + h) * 128 + (((kk * 4 + g) ^ (h & 7)) << 4);
        af[mf] = *(const s16x8*)((const char*)sA + aoff);
      }
#pragma unroll
      for (int nf = 0; nf < 4; ++nf) {
        int boff = (colbase + nf * 16 + h) * 128 + (((kk * 4 + g) ^ (h & 7)) << 4);
        bfr[nf] = *(const s16x8*)((const char*)sB + boff);
      }
#pragma unroll
      for (int mf = 0; mf < 4; ++mf)
#pragma unroll
        for (int nf = 0; nf < 4; ++nf)
          acc[mf][nf] = __builtin_amdgcn_mfma_f32_16x16x32_bf16(
              af[mf], bfr[nf], acc[mf][nf], 0, 0, 0);
    }
  }

  if (z < 2) {
    // Q'/K' layout: rows = attention row index (ch%256), cols = d hi|lo
#pragma unroll
    for (int mf = 0; mf < 4; ++mf) {
      int mbase = m0 + mf * 16 + g * 4;
#pragma unroll
      for (int nf = 0; nf < 4; ++nf) {
        int n = n0 + colbase + nf * 16 + h;
        int bb = n >> 6, d = n & 63;
#pragma unroll
        for (int qq = 0; qq < 4; ++qq) {
          int m = mbase + qq;
          int cc = m >> 8;
          size_t rowb = ((size_t)(bb * 2 + cc) * 256 + (m & 255)) * 128;
          float vvv = acc[mf][nf][qq];
          unsigned short hi = f2bf(vvv);
          unsigned short lo = f2bf(vvv - bf2f(hi));
          Cq[rowb + d] = hi;
          Cq[rowb + 64 + d] = lo;
        }
      }
    }
  } else {
    // V^T layout: rows = d, cols = j hi|lo
#pragma unroll
    for (int mf = 0; mf < 4; ++mf) {
      int mbase = m0 + mf * 16 + g * 4;
      int cc = mbase >> 8;
      int mc = mbase & 255;
#pragma unroll
      for (int nf = 0; nf < 4; ++nf) {
        int n = n0 + colbase + nf * 16 + h;
        int bb = n >> 6, d = n & 63;
        size_t rowb = ((size_t)(bb * 2 + cc) * 64 + d) * 512;
        ushort4 hv, lv;
        float v0 = acc[mf][nf][0], v1 = acc[mf][nf][1];
        float v2 = acc[mf][nf][2], v3 = acc[mf][nf][3];
        hv.x = f2bf(v0); hv.y = f2bf(v1); hv.z = f2bf(v2); hv.w = f2bf(v3);
        lv.x = f2bf(v0 - bf2f(hv.x)); lv.y = f2bf(v1 - bf2f(hv.y));
        lv.z = f2bf(v2 - bf2f(hv.z)); lv.w = f2bf(v3 - bf2f(hv.w));
        *(ushort4*)&Cq[rowb + mc] = hv;
        *(ushort4*)&Cq[rowb + 256 + mc] = lv;
      }
    }
  }
}

// ======================= final GEMM: deep pipe + split-K ===================
// G[ks] = X'(1024x4096) * lwp^T over K'-half. BM=256, BN=128, BK=64,
// 8 waves, 4x4 16x16 frags/wave, 3 LDS buffers (147KB), 4 phases/K-tile,
// counted vmcnt(6). Grid (32,8) ONLY (hardcoded swizzle).
__global__ __launch_bounds__(512, 2) void gemm_final_kernel(
    const unsigned short* __restrict__ A, const unsigned short* __restrict__ B,
    float* __restrict__ C)
{
  __shared__ unsigned short lds[73728];    // 147456 B = 3 x 49152
  const int t = threadIdx.x;

  const int flat = blockIdx.y * 32 + blockIdx.x;  // 0..255
  const int xcd = flat & 7;
  const int ii = flat >> 3;                 // 0..31
  const int n0 = (xcd * 4 + (ii & 3)) * 128;
  const int rem = ii >> 2;                  // 0..7
  const int m0 = (rem & 3) * 256;
  const int ks = rem >> 2;                  // 0..1
  const int base = ks * 48;

  const int K = 2048, twoK = 4096, Km = 2047;

  const int lane = t & 63;
  const int wv = t >> 6;
  const int wm = wv & 3, wn = wv >> 2;
  const int h = lane & 15, g = lane >> 4;

  f32x4 acc[4][4];
#pragma unroll
  for (int mf = 0; mf < 4; ++mf)
#pragma unroll
    for (int nf = 0; nf < 4; ++nf)
      acc[mf][nf] = (f32x4){0.f, 0.f, 0.f, 0.f};

  int arow[4], ablk[4], brow[2], bblk[2];
#pragma unroll
  for (int it = 0; it < 4; ++it) {
    int s = it * 512 + t;
    arow[it] = s >> 3;
    ablk[it] = (t & 7) ^ (arow[it] & 7);
  }
#pragma unroll
  for (int it = 0; it < 2; ++it) {
    int s = it * 512 + t;
    brow[it] = s >> 3;
    bblk[it] = (t & 7) ^ (brow[it] & 7);
  }

  auto issueA = [&](int buf, int tt, int it) {
    int kp = tt * 64 + ablk[it] * 8;
    int ac = (kp < twoK) ? (kp & Km) : (kp - K);
    __builtin_amdgcn_global_load_lds(
        (gas_t)(const void*)(A + (size_t)(m0 + arow[it]) * twoK + ac),
        (las_t)(void*)((char*)lds + (buf * 49152 + it * 8192 + t * 16)), 16, 0, 0);
  };
  auto issueB = [&](int buf, int tt, int it) {
    int kp = tt * 64 + bblk[it] * 8;
    int bc = (kp < twoK) ? kp : (kp - twoK);
    __builtin_amdgcn_global_load_lds(
        (gas_t)(const void*)(B + (size_t)(n0 + brow[it]) * twoK + bc),
        (las_t)(void*)((char*)lds + (buf * 49152 + 32768 + it * 8192 + t * 16)), 16, 0, 0);
  };

  const int aoffb = (wm * 64 + h) * 128;
  const int boffb = 32768 + (wn * 64 + h) * 128;
  int colx[2];
  colx[0] = ((g) ^ (h & 7)) << 4;
  colx[1] = ((4 + g) ^ (h & 7)) << 4;

  auto rdA = [&](int buf, int kk, int mf) -> s16x8 {
    return *(const s16x8*)((const char*)lds + (buf * 49152 + aoffb + mf * 2048 + colx[kk]));
  };
  auto rdB = [&](int buf, int kk, int nf) -> s16x8 {
    return *(const s16x8*)((const char*)lds + (buf * 49152 + boffb + nf * 2048 + colx[kk]));
  };

#define MFMA_ROW2(A0, A1, A2, A3, BB, NF) \
  acc[0][NF] = __builtin_amdgcn_mfma_f32_16x16x32_bf16(A0, BB, acc[0][NF], 0, 0, 0); \
  acc[1][NF] = __builtin_amdgcn_mfma_f32_16x16x32_bf16(A1, BB, acc[1][NF], 0, 0, 0); \
  acc[2][NF] = __builtin_amdgcn_mfma_f32_16x16x32_bf16(A2, BB, acc[2][NF], 0, 0, 0); \
  acc[3][NF] = __builtin_amdgcn_mfma_f32_16x16x32_bf16(A3, BB, acc[3][NF], 0, 0, 0);

#pragma unroll
  for (int it = 0; it < 4; ++it) issueA(0, base, it);
#pragma unroll
  for (int it = 0; it < 2; ++it) issueB(0, base, it);
#pragma unroll
  for (int it = 0; it < 4; ++it) issueA(1, base + 1, it);
#pragma unroll
  for (int it = 0; it < 2; ++it) issueB(1, base + 1, it);
  asm volatile("s_waitcnt vmcnt(6)" ::: "memory");
  __builtin_amdgcn_sched_barrier(0);
  __builtin_amdgcn_s_barrier();
  __builtin_amdgcn_sched_barrier(0);

  int bR = 0;
  for (int tt = base; tt <= base + 45; ++tt) {
    const int bn2 = (bR >= 1) ? bR - 1 : 2;      // (bR+2)%3
    s16x8 a0 = rdA(bR, 0, 0), a1 = rdA(bR, 0, 1), a2 = rdA(bR, 0, 2), a3 = rdA(bR, 0, 3);
    s16x8 b0 = rdB(bR, 0, 0), b1 = rdB(bR, 0, 1);
    issueA(bn2, tt + 2, 0); issueA(bn2, tt + 2, 1);
    __builtin_amdgcn_s_barrier();
    __builtin_amdgcn_s_setprio(1);
    MFMA_ROW2(a0, a1, a2, a3, b0, 0)
    MFMA_ROW2(a0, a1, a2, a3, b1, 1)
    __builtin_amdgcn_s_setprio(0);
    __builtin_amdgcn_s_barrier();
    s16x8 b2 = rdB(bR, 0, 2), b3 = rdB(bR, 0, 3);
    issueA(bn2, tt + 2, 2); issueA(bn2, tt + 2, 3);
    __builtin_amdgcn_s_barrier();
    __builtin_amdgcn_s_setprio(1);
    MFMA_ROW2(a0, a1, a2, a3, b2, 2)
    MFMA_ROW2(a0, a1, a2, a3, b3, 3)
    __builtin_amdgcn_s_setprio(0);
    __builtin_amdgcn_s_barrier();
    a0 = rdA(bR, 1, 0); a1 = rdA(bR, 1, 1); a2 = rdA(bR, 1, 2); a3 = rdA(bR, 1, 3);
    b0 = rdB(bR, 1, 0); b1 = rdB(bR, 1, 1);
    issueB(bn2, tt + 2, 0);
    __builtin_amdgcn_s_barrier();
    __builtin_amdgcn_s_setprio(1);
    MFMA_ROW2(a0, a1, a2, a3, b0, 0)
    MFMA_ROW2(a0, a1, a2, a3, b1, 1)
    __builtin_amdgcn_s_setprio(0);
    __builtin_amdgcn_s_barrier();
    b2 = rdB(bR, 1, 2); b3 = rdB(bR, 1, 3);
    issueB(bn2, tt + 2, 1);
    __builtin_amdgcn_s_barrier();
    __builtin_amdgcn_s_setprio(1);
    MFMA_ROW2(a0, a1, a2, a3, b2, 2)
    MFMA_ROW2(a0, a1, a2, a3, b3, 3)
    __builtin_amdgcn_s_setprio(0);
    asm volatile("s_waitcnt vmcnt(6)" ::: "memory");
    __builtin_amdgcn_sched_barrier(0);
    __builtin_amdgcn_s_barrier();
    __builtin_amdgcn_sched_barrier(0);
    bR = (bR == 2) ? 0 : bR + 1;
  }

  auto compute_tile = [&](int buf) {
#pragma unroll
    for (int kk = 0; kk < 2; ++kk) {
      s16x8 ta0 = rdA(buf, kk, 0), ta1 = rdA(buf, kk, 1);
      s16x8 ta2 = rdA(buf, kk, 2), ta3 = rdA(buf, kk, 3);
      s16x8 tb0 = rdB(buf, kk, 0), tb1 = rdB(buf, kk, 1);
      s16x8 tb2 = rdB(buf, kk, 2), tb3 = rdB(buf, kk, 3);
      MFMA_ROW2(ta0, ta1, ta2, ta3, tb0, 0)
      MFMA_ROW2(ta0, ta1, ta2, ta3, tb1, 1)
      MFMA_ROW2(ta0, ta1, ta2, ta3, tb2, 2)
      MFMA_ROW2(ta0, ta1, ta2, ta3, tb3, 3)
    }
  };
  compute_tile(bR);
  __syncthreads();
  compute_tile((bR == 2) ? 0 : bR + 1);
#undef MFMA_ROW2

  float* Cks = C + (size_t)ks * 4194304;
#pragma unroll
  for (int mf = 0; mf < 4; ++mf) {
    int mbase = m0 + wm * 64 + mf * 16 + g * 4;
#pragma unroll
    for (int nf = 0; nf < 4; ++nf) {
      int n = n0 + wn * 64 + nf * 16 + h;
#pragma unroll
      for (int qq = 0; qq < 4; ++qq)
        Cks[(size_t)(mbase + qq) * 4096 + n] = acc[mf][nf][qq];
    }
  }
}

// ======== Attention (z<64) | linw split+rowsum (z>=64) =====================
__global__ __launch_bounds__(256) void attn_rs_kernel(
    const unsigned short* __restrict__ qp, const unsigned short* __restrict__ kp,
    const unsigned short* __restrict__ vtp, const float* __restrict__ pos,
    unsigned short* __restrict__ Xp,
    const float* __restrict__ linw, unsigned short* __restrict__ lwp,
    float* __restrict__ rs)
{
  __shared__ char smem[59904];

  const int t = threadIdx.x;

  if (blockIdx.z >= 64) {
    // ---- split_rs path: row r of linw [4096][2048] ----
    float* wsum = (float*)smem;
    const int r = (blockIdx.z - 64) * 16 + blockIdx.y * 8 + blockIdx.x;  // 0..4095
    const float* rowp = linw + (size_t)r * 2048 + t * 8;
    float4 x0 = *(const float4*)rowp;
    float4 x1 = *(const float4*)(rowp + 4);
    unsigned short h0 = f2bf(x0.x), h1 = f2bf(x0.y), h2 = f2bf(x0.z), h3 = f2bf(x0.w);
    unsigned short h4 = f2bf(x1.x), h5 = f2bf(x1.y), h6 = f2bf(x1.z), h7 = f2bf(x1.w);
    uint4 hp, lp;
    hp.x = (unsigned)h0 | ((unsigned)h1 << 16);
    hp.y = (unsigned)h2 | ((unsigned)h3 << 16);
    hp.z = (unsigned)h4 | ((unsigned)h5 << 16);
    hp.w = (unsigned)h6 | ((unsigned)h7 << 16);
    lp.x = (unsigned)f2bf(x0.x - bf2f(h0)) | ((unsigned)f2bf(x0.y - bf2f(h1)) << 16);
    lp.y = (unsigned)f2bf(x0.z - bf2f(h2)) | ((unsigned)f2bf(x0.w - bf2f(h3)) << 16);
    lp.z = (unsigned)f2bf(x1.x - bf2f(h4)) | ((unsigned)f2bf(x1.y - bf2f(h5)) << 16);
    lp.w = (unsigned)f2bf(x1.z - bf2f(h6)) | ((unsigned)f2bf(x1.w - bf2f(h7)) << 16);
    unsigned short* dr = lwp + (size_t)r * 4096 + t * 8;
    *(uint4*)dr = hp;
    *(uint4*)(dr + 2048) = lp;
    float s = x0.x + x0.y + x0.z + x0.w + x1.x + x1.y + x1.z + x1.w;
#pragma unroll
    for (int off = 1; off < 64; off <<= 1) s += __shfl_xor(s, off, 64);
    if ((t & 63) == 0) wsum[t >> 6] = s;
    __syncthreads();
    if (t == 0) rs[r] = wsum[0] + wsum[1] + wsum[2] + wsum[3];
    return;
  }

  unsigned short* qs = (unsigned short*)smem;
  unsigned short* kv = (unsigned short*)(smem + 8704);
  float* sc = (float*)(smem + 26112);
  unsigned short* ps = (unsigned short*)(smem + 26112);

  const int rt = blockIdx.x, cc = blockIdx.y, b = blockIdx.z;
  const int i0 = rt * 32;
  const size_t qkbase = (size_t)(b * 2 + cc) * 256;
  const size_t vbase  = (size_t)(b * 2 + cc) * 64;

  const int lane = t & 63, wvv = t >> 6;
  const int h = lane & 15, g = lane >> 4;

#pragma unroll
  for (int rep = 0; rep < 2; ++rep) {
    int s = t + rep * 256;
    int row = s >> 4;
    int blk = s & 15;
    int4 val = *(const int4*)(qp + (qkbase + i0 + row) * 128 + blk * 8);
    *(int4*)((char*)qs + row * 272 + blk * 16) = val;
  }

  for (int c = 0; c < 4; ++c) {
    __syncthreads();
#pragma unroll
    for (int p2 = 0; p2 < 4; ++p2) {
      int s = t + p2 * 256;
      int row = s >> 4;
      int blk = s & 15;
      int4 val = *(const int4*)(kp + (qkbase + c * 64 + row) * 128 + blk * 8);
      *(int4*)((char*)kv + row * 272 + blk * 16) = val;
    }
    __syncthreads();
    f32x4 acc2[2];
    acc2[0] = (f32x4){0.f, 0.f, 0.f, 0.f};
    acc2[1] = (f32x4){0.f, 0.f, 0.f, 0.f};
#pragma unroll
    for (int kk = 0; kk < 6; ++kk) {
      int abase = (kk < 2) ? kk * 32 : (kk < 4) ? 64 + (kk - 2) * 32 : (kk - 4) * 32;
      int bbase = (kk < 2) ? kk * 32 : (kk < 4) ? (kk - 2) * 32 : 64 + (kk - 4) * 32;
      s16x8 bfrag = *(const s16x8*)((char*)kv + (wvv * 16 + h) * 272 + (bbase + g * 8) * 2);
#pragma unroll
      for (int mf = 0; mf < 2; ++mf) {
        s16x8 afrag = *(const s16x8*)((char*)qs + (mf * 16 + h) * 272 + (abase + g * 8) * 2);
        acc2[mf] = __builtin_amdgcn_mfma_f32_16x16x32_bf16(afrag, bfrag, acc2[mf], 0, 0, 0);
      }
    }
#pragma unroll
    for (int mf = 0; mf < 2; ++mf)
#pragma unroll
      for (int qq = 0; qq < 4; ++qq) {
        int row = mf * 16 + g * 4 + qq;
        int j = c * 64 + wvv * 16 + h;
        sc[row * 264 + j] = acc2[mf][qq] * 0.125f +
            pos[((size_t)cc * 256 + i0 + row) * 256 + j];
      }
  }
  __syncthreads();

  {
    const int r = t >> 3, j8 = t & 7;
    float e[32];
    float mx = -3.4e38f;
#pragma unroll
    for (int jj = 0; jj < 32; ++jj) {
      e[jj] = sc[r * 264 + j8 + 8 * jj];
      mx = fmaxf(mx, e[jj]);
    }
#pragma unroll
    for (int mset = 1; mset < 8; mset <<= 1) mx = fmaxf(mx, __shfl_xor(mx, mset, 64));
    float sum = 0.f;
#pragma unroll
    for (int jj = 0; jj < 32; ++jj) {
      e[jj] = expf(e[jj] - mx);
      sum += e[jj];
    }
#pragma unroll
    for (int mset = 1; mset < 8; mset <<= 1) sum += __shfl_xor(sum, mset, 64);
    float inv = 1.f / sum;
    __syncthreads();
#pragma unroll
    for (int jj = 0; jj < 32; ++jj) {
      float pv = e[jj] * inv;
      unsigned short hi = f2bf(pv);
      unsigned short lo = f2bf(pv - bf2f(hi));
      int j = j8 + 8 * jj;
      ps[r * 528 + j] = hi;
      ps[r * 528 + 264 + j] = lo;
    }
  }

  f32x4 oacc[2];
  oacc[0] = (f32x4){0.f, 0.f, 0.f, 0.f};
  oacc[1] = (f32x4){0.f, 0.f, 0.f, 0.f};
  for (int c = 0; c < 4; ++c) {
    __syncthreads();
#pragma unroll
    for (int p2 = 0; p2 < 4; ++p2) {
      int s = t + p2 * 256, row = s >> 4, blk = s & 15;
      int col = (blk < 8) ? (c * 64 + blk * 8) : (256 + c * 64 + (blk - 8) * 8);
      int4 val = *(const int4*)(vtp + (vbase + row) * 512 + col);
      *(int4*)((char*)kv + row * 272 + blk * 16) = val;
    }
    __syncthreads();
#pragma unroll
    for (int kk = 0; kk < 6; ++kk) {
      int abase = (kk < 2) ? (c * 64 + kk * 32)
                : (kk < 4) ? (264 + c * 64 + (kk - 2) * 32)
                           : (c * 64 + (kk - 4) * 32);
      int bbase = (kk < 2) ? kk * 32 : (kk < 4) ? (kk - 2) * 32 : 64 + (kk - 4) * 32;
      s16x8 bfrag = *(const s16x8*)((char*)kv + (wvv * 16 + h) * 272 + (bbase + g * 8) * 2);
#pragma unroll
      for (int mf = 0; mf < 2; ++mf) {
        s16x8 afrag = *(const s16x8*)((char*)ps + (mf * 16 + h) * 1056 + (abase + g * 8) * 2);
        oacc[mf] = __builtin_amdgcn_mfma_f32_16x16x32_bf16(afrag, bfrag, oacc[mf], 0, 0, 0);
      }
    }
  }
  {
    int Xrow = b * 16 + cc * 8 + wvv * 2 + (h >> 3);
    int c7 = h & 7;
#pragma unroll
    for (int mf = 0; mf < 2; ++mf)
#pragma unroll
      for (int qq = 0; qq < 4; ++qq) {
        int dd = i0 + mf * 16 + g * 4 + qq;
        float vvv = oacc[mf][qq];
        unsigned short hi = f2bf(vvv);
        unsigned short lo = f2bf(vvv - bf2f(hi));
        size_t base = (size_t)Xrow * 4096 + dd * 8 + c7;
        Xp[base] = hi;
        Xp[base + 2048] = lo;
      }
  }
}

// ======================= epilogue: out = c1w*(G0+G1) + c1b*rs + lin_b =====
__global__ __launch_bounds__(256) void epilogue_kernel(
    const float* __restrict__ G, const float* __restrict__ rs,
    const float* __restrict__ c1w, const float* __restrict__ c1b,
    const float* __restrict__ linb, float* __restrict__ out)
{
  __shared__ float W[512];
  __shared__ float Bp[32];
  const int t = threadIdx.x;
  const int ntile = blockIdx.x;   // 0..15
  const int b = blockIdx.y;       // 0..63
  W[t] = c1w[t];
  W[t + 256] = c1w[t + 256];
  if (t < 32) Bp[t] = c1b[t];
  __syncthreads();
  const int n = ntile * 256 + t;
  float gv[16];
#pragma unroll
  for (int ch = 0; ch < 16; ++ch) {
    size_t off = (size_t)(b * 16 + ch) * 4096 + n;
    gv[ch] = G[off] + G[4194304 + off];
  }
  const float rsn = rs[n];
  const float lbn = linb[n];
#pragma unroll
  for (int o = 0; o < 32; ++o) {
    float s = lbn + Bp[o] * rsn;
#pragma unroll
    for (int ch = 0; ch < 16; ++ch) s = fmaf(W[o * 16 + ch], gv[ch], s);
    out[(size_t)(b * 32 + o) * 4096 + n] = s;
  }
}

// ======================= launch ============================================
extern "C" void kernel_launch(void* const* d_in, const int* in_sizes, int n_in,
                              void* d_out, int out_size, void* d_ws, size_t ws_size,
                              hipStream_t stream) {
  const float* q    = (const float*)d_in[0];
  const float* k    = (const float*)d_in[1];
  const float* v    = (const float*)d_in[2];
  const float* dwk  = (const float*)d_in[3];
  const float* bng  = (const float*)d_in[4];
  const float* bnb  = (const float*)d_in[5];
  const float* bnm  = (const float*)d_in[6];
  const float* bnv  = (const float*)d_in[7];
  const float* pwk  = (const float*)d_in[8];
  const float* pos  = (const float*)d_in[9];
  const float* c1w  = (const float*)d_in[10];
  const float* c1b  = (const float*)d_in[11];
  const float* linw = (const float*)d_in[12];
  const float* linb = (const float*)d_in[13];
  float* out = (float*)d_out;

  if (ws_size < 50331648u) return;

  char* ws = (char*)d_ws;
  unsigned short* qp   = (unsigned short*)(ws + 0);          //  8,388,608
  unsigned short* kpp  = (unsigned short*)(ws + 8388608);    //  8,388,608
  unsigned short* vtp  = (unsigned short*)(ws + 16777216);   //  8,388,608
  unsigned short* tTp  = (unsigned short*)(ws + 25165824);   // 25,165,824
  unsigned short* pwkp = (unsigned short*)d_out;             //  3,145,728 (d_out scratch)
  unsigned short* Xp   = (unsigned short*)(ws + 41943040);   //  8,388,608 (over tTp slab 2)
  float*          rs   = (float*)(ws + 33554432);            //     16,384 (tTp slab-1 tail)
  unsigned short* lwp  = (unsigned short*)d_out;             // 33,554,432 (d_out scratch)
  float*          G    = (float*)(ws + 0);                   // 33,554,432 (G[2], over qp/kpp/vtp/slab0)

  // 1) dwconv+BN+GELU (y<3) + pwk split (y==3)
  stageA_split_kernel<<<dim3(1024, 4), 256, 0, stream>>>(
      q, k, v, dwk, bng, bnb, bnm, bnv, tTp, pwk, pwkp);

  // 2) pointwise GEMMs (2-wave, 64x64/wave) -> qp/kpp/vtp
  gemm_split_kernel<<<dim3(32, 8, 3), 128, 0, stream>>>(pwkp, tTp, qp);

  // 3) attention (z<64) -> Xp  |  linw split+rowsum (z>=64) -> lwp, rs
  attn_rs_kernel<<<dim3(8, 2, 320), 256, 0, stream>>>(
      qp, kpp, vtp, pos, Xp, linw, lwp, rs);

  // 4) G[ks] = X' * lwp^T partials  (deep pipe, split-K, 256 blocks)
  gemm_final_kernel<<<dim3(32, 8), 512, 0, stream>>>(Xp, lwp, G);

  // 5) out = c1w*(G0+G1) + c1b*rs + lin_b
  epilogue_kernel<<<dim3(16, 64), 256, 0, stream>>>(G, rs, c1w, c1b, linb, out);
}